// Round 3
// baseline (611.286 us; speedup 1.0000x reference)
//
#include <hip/hip_runtime.h>
#include <math.h>
#include <float.h>

#define BN_EPS 1e-5f

__device__ __forceinline__ float readlane_f(float v, int l) {
    return __int_as_float(__builtin_amdgcn_readlane(__float_as_int(v), l));
}

// ---------------------------------------------------------------------------
// Kernel 1: in-degree histogram (4 edges/thread)
// ---------------------------------------------------------------------------
__global__ __launch_bounds__(256) void deg_hist(
    const int* __restrict__ dst, int* deg, int E)
{
    int base = (blockIdx.x * 256 + threadIdx.x) * 4;
    if (base + 3 < E) {
        int4 d = *(const int4*)(dst + base);
        atomicAdd(&deg[d.x], 1);
        atomicAdd(&deg[d.y], 1);
        atomicAdd(&deg[d.z], 1);
        atomicAdd(&deg[d.w], 1);
    } else {
        for (int e = base; e < E; ++e) atomicAdd(&deg[dst[e]], 1);
    }
}

// ---------------------------------------------------------------------------
// Kernel 2a: per-block exclusive scan of deg (256/block), write block sums
// ---------------------------------------------------------------------------
__global__ __launch_bounds__(256) void scan_block(
    const int* __restrict__ deg, int* __restrict__ excl,
    int* __restrict__ bsum, int N)
{
    int tid = threadIdx.x;
    int i = blockIdx.x * 256 + tid;
    int lane = tid & 63, wave = tid >> 6;
    int orig = (i < N) ? deg[i] : 0;
    int v = orig;
    #pragma unroll
    for (int d = 1; d < 64; d <<= 1) {
        int t = __shfl_up(v, d);
        if (lane >= d) v += t;
    }
    __shared__ int ws[4];
    if (lane == 63) ws[wave] = v;
    __syncthreads();
    int woff = 0;
    for (int w = 0; w < wave; ++w) woff += ws[w];
    int incl = v + woff;
    if (i < N) excl[i] = incl - orig;
    if (tid == 255) bsum[blockIdx.x] = incl;
}

// ---------------------------------------------------------------------------
// Kernel 2b: scan the block sums (NB <= 512), in place -> exclusive offsets
// ---------------------------------------------------------------------------
__global__ __launch_bounds__(512) void scan_tops(int* bsum, int NB)
{
    __shared__ int s[512];
    int tid = threadIdx.x;
    int v = (tid < NB) ? bsum[tid] : 0;
    s[tid] = v;
    __syncthreads();
    for (int d = 1; d < 512; d <<= 1) {
        int t = (tid >= d) ? s[tid - d] : 0;
        __syncthreads();
        s[tid] += t;
        __syncthreads();
    }
    if (tid < NB) bsum[tid] = s[tid] - v;   // exclusive
}

// ---------------------------------------------------------------------------
// Kernel 2c: combine -> row_start[i], cursor[i]; row_start[N] = E
// ---------------------------------------------------------------------------
__global__ __launch_bounds__(256) void scan_add(
    const int* __restrict__ excl, const int* __restrict__ bsum,
    int* __restrict__ row_start, int* __restrict__ cursor, int N, int E)
{
    int i = blockIdx.x * 256 + threadIdx.x;
    if (i < N) {
        int r = excl[i] + bsum[i >> 8];
        row_start[i] = r;
        cursor[i] = r;
    }
    if (i == 0) row_start[N] = E;
}

// ---------------------------------------------------------------------------
// Kernel 3: place edge src ids into CSR slots (counting-sort scatter)
// ---------------------------------------------------------------------------
__global__ __launch_bounds__(256) void edge_place(
    const int* __restrict__ src, const int* __restrict__ dst,
    int* cursor, int* __restrict__ eord, int E)
{
    int base = (blockIdx.x * 256 + threadIdx.x) * 4;
    if (base + 3 < E) {
        int4 d = *(const int4*)(dst + base);
        int4 s = *(const int4*)(src + base);
        eord[atomicAdd(&cursor[d.x], 1)] = s.x;
        eord[atomicAdd(&cursor[d.y], 1)] = s.y;
        eord[atomicAdd(&cursor[d.z], 1)] = s.z;
        eord[atomicAdd(&cursor[d.w], 1)] = s.w;
    } else {
        for (int e = base; e < E; ++e)
            eord[atomicAdd(&cursor[dst[e]], 1)] = src[e];
    }
}

// ---------------------------------------------------------------------------
// Kernel 4: fused gather + MLP.  Wave per node, 8-way ILP in the neighbor
// gather (8 independent accumulators -> 8 outstanding global loads).
// ---------------------------------------------------------------------------
__global__ __launch_bounds__(256, 4) void fused_mlp(
    const float* __restrict__ x,
    const int* __restrict__ eord, const int* __restrict__ row_start,
    const float* __restrict__ W1, const float* __restrict__ b1,
    const float* __restrict__ W2, const float* __restrict__ b2,
    const float* __restrict__ Wg, const float* __restrict__ bg,
    float* __restrict__ h_out, float* __restrict__ gate_out, int N)
{
    __shared__ float W1s[64 * 64];
    __shared__ float W2s[64 * 64];
    __shared__ float b1s[64], b2s[64], Wgs[64];

    int tid = threadIdx.x;
    for (int i = tid; i < 64 * 64; i += 256) {
        W1s[i] = W1[i];
        W2s[i] = W2[i];
    }
    if (tid < 64) {
        b1s[tid] = b1[tid];
        b2s[tid] = b2[tid];
        Wgs[tid] = Wg[tid];
    }
    __syncthreads();

    float bgv = bg[0];
    int lane = tid & 63;
    int wave = tid >> 6;
    int stride = gridDim.x * 4;

    for (int node = blockIdx.x * 4 + wave; node < N; node += stride) {
        size_t row = (size_t)node * 64;
        int beg = row_start[node];
        int end = row_start[node + 1];

        float v0 = x[row + lane];
        float v1 = 0.f, v2 = 0.f, v3 = 0.f, v4 = 0.f, v5 = 0.f, v6 = 0.f, v7 = 0.f;

        for (int base = beg; base < end; base += 64) {
            int ei = (base + lane < end) ? eord[base + lane] : 0;
            int cnt = end - base; if (cnt > 64) cnt = 64;
            int j = 0;
            for (; j + 8 <= cnt; j += 8) {
                int s0 = __builtin_amdgcn_readlane(ei, j + 0);
                int s1 = __builtin_amdgcn_readlane(ei, j + 1);
                int s2 = __builtin_amdgcn_readlane(ei, j + 2);
                int s3 = __builtin_amdgcn_readlane(ei, j + 3);
                int s4 = __builtin_amdgcn_readlane(ei, j + 4);
                int s5 = __builtin_amdgcn_readlane(ei, j + 5);
                int s6 = __builtin_amdgcn_readlane(ei, j + 6);
                int s7 = __builtin_amdgcn_readlane(ei, j + 7);
                float t0 = x[(size_t)s0 * 64 + lane];
                float t1 = x[(size_t)s1 * 64 + lane];
                float t2 = x[(size_t)s2 * 64 + lane];
                float t3 = x[(size_t)s3 * 64 + lane];
                float t4 = x[(size_t)s4 * 64 + lane];
                float t5 = x[(size_t)s5 * 64 + lane];
                float t6 = x[(size_t)s6 * 64 + lane];
                float t7 = x[(size_t)s7 * 64 + lane];
                v0 += t0; v1 += t1; v2 += t2; v3 += t3;
                v4 += t4; v5 += t5; v6 += t6; v7 += t7;
            }
            for (; j < cnt; ++j) {
                int s = __builtin_amdgcn_readlane(ei, j);
                v1 += x[(size_t)s * 64 + lane];
            }
        }
        float v = ((v0 + v1) + (v2 + v3)) + ((v4 + v5) + (v6 + v7));

        float acc = b1s[lane];
        #pragma unroll
        for (int k = 0; k < 64; ++k)
            acc = fmaf(readlane_f(v, k), W1s[k * 64 + lane], acc);
        float h1 = fmaxf(acc, 0.f);

        float acc2 = b2s[lane];
        #pragma unroll
        for (int k = 0; k < 64; ++k)
            acc2 = fmaf(readlane_f(h1, k), W2s[k * 64 + lane], acc2);
        float h2 = fmaxf(acc2, 0.f);

        h_out[row + lane] = h2;

        float gp = h2 * Wgs[lane];
        #pragma unroll
        for (int off = 32; off; off >>= 1)
            gp += __shfl_xor(gp, off);
        if (lane == 0)
            gate_out[node] = gp + bgv;
    }
}

// ---------------------------------------------------------------------------
// Kernel 5: per-graph softmax-attention pooling + BN(eval) + linear + lsm.
// ---------------------------------------------------------------------------
__global__ __launch_bounds__(256) void pool_final(
    const float* __restrict__ h, const float* __restrict__ gate,
    const int* __restrict__ batch,
    const float* __restrict__ gamma_, const float* __restrict__ beta_,
    const float* __restrict__ mean_, const float* __restrict__ var_,
    const float* __restrict__ Wl, const float* __restrict__ bl,
    float* __restrict__ out, int N)
{
    int g = blockIdx.x;
    int tid = threadIdx.x;

    int lo = 0, hi = N;
    while (lo < hi) { int mid = (lo + hi) >> 1; if (batch[mid] < g) lo = mid + 1; else hi = mid; }
    int start = lo;
    hi = N;
    while (lo < hi) { int mid = (lo + hi) >> 1; if (batch[mid] < g + 1) lo = mid + 1; else hi = mid; }
    int end = lo;

    __shared__ float red[4];
    __shared__ float pool_s[4 * 64];

    int lane = tid & 63;
    int wave = tid >> 6;

    float m = -FLT_MAX;
    for (int i = start + tid; i < end; i += 256) m = fmaxf(m, gate[i]);
    #pragma unroll
    for (int off = 32; off; off >>= 1) m = fmaxf(m, __shfl_xor(m, off));
    if (lane == 0) red[wave] = m;
    __syncthreads();
    m = fmaxf(fmaxf(red[0], red[1]), fmaxf(red[2], red[3]));
    __syncthreads();

    float s = 0.f;
    for (int i = start + tid; i < end; i += 256) s += expf(gate[i] - m);
    #pragma unroll
    for (int off = 32; off; off >>= 1) s += __shfl_xor(s, off);
    if (lane == 0) red[wave] = s;
    __syncthreads();
    s = red[0] + red[1] + red[2] + red[3];

    float acc = 0.f;
    for (int i = start + wave; i < end; i += 4) {
        float e = expf(gate[i] - m);
        acc = fmaf(e, h[(size_t)i * 64 + lane], acc);
    }
    pool_s[wave * 64 + lane] = acc;
    __syncthreads();

    if (wave == 0) {
        float p = pool_s[lane] + pool_s[64 + lane] + pool_s[128 + lane] + pool_s[192 + lane];
        p = (end > start) ? (p / s) : 0.f;
        float nrm = (p - mean_[lane]) / sqrtf(var_[lane] + BN_EPS) * gamma_[lane] + beta_[lane];
        float l0 = nrm * Wl[lane * 2 + 0];
        float l1 = nrm * Wl[lane * 2 + 1];
        #pragma unroll
        for (int off = 32; off; off >>= 1) {
            l0 += __shfl_xor(l0, off);
            l1 += __shfl_xor(l1, off);
        }
        if (lane == 0) {
            l0 += bl[0];
            l1 += bl[1];
            float mx = fmaxf(l0, l1);
            float lse = mx + logf(expf(l0 - mx) + expf(l1 - mx));
            out[g * 2 + 0] = l0 - lse;
            out[g * 2 + 1] = l1 - lse;
        }
    }
}

// ---------------------------------------------------------------------------
extern "C" void kernel_launch(void* const* d_in, const int* in_sizes, int n_in,
                              void* d_out, int out_size, void* d_ws, size_t ws_size,
                              hipStream_t stream)
{
    const float* x     = (const float*)d_in[0];
    const int*   eidx  = (const int*)d_in[1];   // [2, E]: row0=src, row1=dst
    const int*   batch = (const int*)d_in[2];
    const float* W1    = (const float*)d_in[3];
    const float* b1    = (const float*)d_in[4];
    const float* W2    = (const float*)d_in[5];
    const float* b2    = (const float*)d_in[6];
    const float* Wg    = (const float*)d_in[7];
    const float* bg    = (const float*)d_in[8];
    const float* bng   = (const float*)d_in[9];
    const float* bnb   = (const float*)d_in[10];
    const float* bnm   = (const float*)d_in[11];
    const float* bnv   = (const float*)d_in[12];
    const float* Wl    = (const float*)d_in[13];
    const float* bl    = (const float*)d_in[14];
    float* out = (float*)d_out;

    int N = in_sizes[0] / 64;
    int E = in_sizes[1] / 2;
    int G = out_size / 2;
    int NB = (N + 255) / 256;   // scan blocks (<= 512 required)

    char* w = (char*)d_ws;
    float* h        = (float*)w;                 w += (size_t)N * 64 * sizeof(float);
    float* gate     = (float*)w;                 w += (size_t)N * sizeof(float);
    int*   deg      = (int*)w;                   w += (size_t)N * sizeof(int);
    int*   excl     = (int*)w;                   w += (size_t)N * sizeof(int);
    int*   row_start= (int*)w;                   w += (size_t)(N + 1) * sizeof(int);
    int*   cursor   = (int*)w;                   w += (size_t)N * sizeof(int);
    int*   bsum     = (int*)w;                   w += (size_t)512 * sizeof(int);
    int*   eord     = (int*)w;                   // E ints

    const int* src = eidx;
    const int* dst = eidx + E;

    hipMemsetAsync(deg, 0, (size_t)N * sizeof(int), stream);

    int EB4 = (E + 1023) / 1024;  // 4 edges per thread
    deg_hist  <<<EB4, 256, 0, stream>>>(dst, deg, E);
    scan_block<<<NB, 256, 0, stream>>>(deg, excl, bsum, N);
    scan_tops <<<1, 512, 0, stream>>>(bsum, NB);
    scan_add  <<<NB, 256, 0, stream>>>(excl, bsum, row_start, cursor, N, E);
    edge_place<<<EB4, 256, 0, stream>>>(src, dst, cursor, eord, E);

    fused_mlp <<<1024, 256, 0, stream>>>(x, eord, row_start, W1, b1, W2, b2,
                                         Wg, bg, h, gate, N);

    pool_final<<<G, 256, 0, stream>>>(h, gate, batch, bng, bnb, bnm, bnv,
                                      Wl, bl, out, N);
}

// Round 4
// 490.481 us; speedup vs baseline: 1.2463x; 1.2463x over previous
//
#include <hip/hip_runtime.h>
#include <math.h>
#include <float.h>

#define BN_EPS 1e-5f

__device__ __forceinline__ float readlane_f(float v, int l) {
    return __int_as_float(__builtin_amdgcn_readlane(__float_as_int(v), l));
}

// ---------------------------------------------------------------------------
// Kernel 1: in-degree histogram (4 edges/thread)
// ---------------------------------------------------------------------------
__global__ __launch_bounds__(256) void deg_hist(
    const int* __restrict__ dst, int* deg, int E)
{
    int base = (blockIdx.x * 256 + threadIdx.x) * 4;
    if (base + 3 < E) {
        int4 d = *(const int4*)(dst + base);
        atomicAdd(&deg[d.x], 1);
        atomicAdd(&deg[d.y], 1);
        atomicAdd(&deg[d.z], 1);
        atomicAdd(&deg[d.w], 1);
    } else {
        for (int e = base; e < E; ++e) atomicAdd(&deg[dst[e]], 1);
    }
}

// ---------------------------------------------------------------------------
// Kernel 2a: per-block exclusive scan of deg (256/block), write block sums
// ---------------------------------------------------------------------------
__global__ __launch_bounds__(256) void scan_block(
    const int* __restrict__ deg, int* __restrict__ excl,
    int* __restrict__ bsum, int N)
{
    int tid = threadIdx.x;
    int i = blockIdx.x * 256 + tid;
    int lane = tid & 63, wave = tid >> 6;
    int orig = (i < N) ? deg[i] : 0;
    int v = orig;
    #pragma unroll
    for (int d = 1; d < 64; d <<= 1) {
        int t = __shfl_up(v, d);
        if (lane >= d) v += t;
    }
    __shared__ int ws[4];
    if (lane == 63) ws[wave] = v;
    __syncthreads();
    int woff = 0;
    for (int w = 0; w < wave; ++w) woff += ws[w];
    int incl = v + woff;
    if (i < N) excl[i] = incl - orig;
    if (tid == 255) bsum[blockIdx.x] = incl;
}

// ---------------------------------------------------------------------------
// Kernel 2b: scan the block sums (NB <= 512), in place -> exclusive offsets
// ---------------------------------------------------------------------------
__global__ __launch_bounds__(512) void scan_tops(int* bsum, int NB)
{
    __shared__ int s[512];
    int tid = threadIdx.x;
    int v = (tid < NB) ? bsum[tid] : 0;
    s[tid] = v;
    __syncthreads();
    for (int d = 1; d < 512; d <<= 1) {
        int t = (tid >= d) ? s[tid - d] : 0;
        __syncthreads();
        s[tid] += t;
        __syncthreads();
    }
    if (tid < NB) bsum[tid] = s[tid] - v;   // exclusive
}

// ---------------------------------------------------------------------------
// Kernel 2c: combine -> row_start[i], cursor[i]; row_start[N] = E
// ---------------------------------------------------------------------------
__global__ __launch_bounds__(256) void scan_add(
    const int* __restrict__ excl, const int* __restrict__ bsum,
    int* __restrict__ row_start, int* __restrict__ cursor, int N, int E)
{
    int i = blockIdx.x * 256 + threadIdx.x;
    if (i < N) {
        int r = excl[i] + bsum[i >> 8];
        row_start[i] = r;
        cursor[i] = r;
    }
    if (i == 0) row_start[N] = E;
}

// ---------------------------------------------------------------------------
// Kernel 3: place edge src ids into CSR slots (counting-sort scatter)
// ---------------------------------------------------------------------------
__global__ __launch_bounds__(256) void edge_place(
    const int* __restrict__ src, const int* __restrict__ dst,
    int* cursor, int* __restrict__ eord, int E)
{
    int base = (blockIdx.x * 256 + threadIdx.x) * 4;
    if (base + 3 < E) {
        int4 d = *(const int4*)(dst + base);
        int4 s = *(const int4*)(src + base);
        eord[atomicAdd(&cursor[d.x], 1)] = s.x;
        eord[atomicAdd(&cursor[d.y], 1)] = s.y;
        eord[atomicAdd(&cursor[d.z], 1)] = s.z;
        eord[atomicAdd(&cursor[d.w], 1)] = s.w;
    } else {
        for (int e = base; e < E; ++e)
            eord[atomicAdd(&cursor[dst[e]], 1)] = src[e];
    }
}

// ---------------------------------------------------------------------------
// Kernel 4: fused gather + MLP.  Wave per node, 8-way ILP in the neighbor
// gather.  NOTE: no min-waves clamp — LDS (33.8 KB) already caps occupancy
// at 4 blocks/CU; a VGPR clamp to 64 caused scratch spills (R3: +500 MB
// FETCH, +40 MB WRITE).
// ---------------------------------------------------------------------------
__global__ __launch_bounds__(256) void fused_mlp(
    const float* __restrict__ x,
    const int* __restrict__ eord, const int* __restrict__ row_start,
    const float* __restrict__ W1, const float* __restrict__ b1,
    const float* __restrict__ W2, const float* __restrict__ b2,
    const float* __restrict__ Wg, const float* __restrict__ bg,
    float* __restrict__ h_out, float* __restrict__ gate_out, int N)
{
    __shared__ float W1s[64 * 64];
    __shared__ float W2s[64 * 64];
    __shared__ float b1s[64], b2s[64], Wgs[64];

    int tid = threadIdx.x;
    for (int i = tid; i < 64 * 64; i += 256) {
        W1s[i] = W1[i];
        W2s[i] = W2[i];
    }
    if (tid < 64) {
        b1s[tid] = b1[tid];
        b2s[tid] = b2[tid];
        Wgs[tid] = Wg[tid];
    }
    __syncthreads();

    float bgv = bg[0];
    int lane = tid & 63;
    int wave = tid >> 6;
    int stride = gridDim.x * 4;

    for (int node = blockIdx.x * 4 + wave; node < N; node += stride) {
        size_t row = (size_t)node * 64;
        int beg = row_start[node];
        int end = row_start[node + 1];

        float v0 = x[row + lane];
        float v1 = 0.f, v2 = 0.f, v3 = 0.f, v4 = 0.f, v5 = 0.f, v6 = 0.f, v7 = 0.f;

        for (int base = beg; base < end; base += 64) {
            int ei = (base + lane < end) ? eord[base + lane] : 0;
            int cnt = end - base; if (cnt > 64) cnt = 64;
            int j = 0;
            for (; j + 8 <= cnt; j += 8) {
                int s0 = __builtin_amdgcn_readlane(ei, j + 0);
                int s1 = __builtin_amdgcn_readlane(ei, j + 1);
                int s2 = __builtin_amdgcn_readlane(ei, j + 2);
                int s3 = __builtin_amdgcn_readlane(ei, j + 3);
                int s4 = __builtin_amdgcn_readlane(ei, j + 4);
                int s5 = __builtin_amdgcn_readlane(ei, j + 5);
                int s6 = __builtin_amdgcn_readlane(ei, j + 6);
                int s7 = __builtin_amdgcn_readlane(ei, j + 7);
                float t0 = x[(size_t)s0 * 64 + lane];
                float t1 = x[(size_t)s1 * 64 + lane];
                float t2 = x[(size_t)s2 * 64 + lane];
                float t3 = x[(size_t)s3 * 64 + lane];
                float t4 = x[(size_t)s4 * 64 + lane];
                float t5 = x[(size_t)s5 * 64 + lane];
                float t6 = x[(size_t)s6 * 64 + lane];
                float t7 = x[(size_t)s7 * 64 + lane];
                v0 += t0; v1 += t1; v2 += t2; v3 += t3;
                v4 += t4; v5 += t5; v6 += t6; v7 += t7;
            }
            for (; j < cnt; ++j) {
                int s = __builtin_amdgcn_readlane(ei, j);
                v1 += x[(size_t)s * 64 + lane];
            }
        }
        float v = ((v0 + v1) + (v2 + v3)) + ((v4 + v5) + (v6 + v7));

        float acc = b1s[lane];
        #pragma unroll
        for (int k = 0; k < 64; ++k)
            acc = fmaf(readlane_f(v, k), W1s[k * 64 + lane], acc);
        float h1 = fmaxf(acc, 0.f);

        float acc2 = b2s[lane];
        #pragma unroll
        for (int k = 0; k < 64; ++k)
            acc2 = fmaf(readlane_f(h1, k), W2s[k * 64 + lane], acc2);
        float h2 = fmaxf(acc2, 0.f);

        h_out[row + lane] = h2;

        float gp = h2 * Wgs[lane];
        #pragma unroll
        for (int off = 32; off; off >>= 1)
            gp += __shfl_xor(gp, off);
        if (lane == 0)
            gate_out[node] = gp + bgv;
    }
}

// ---------------------------------------------------------------------------
// Kernel 5: per-graph softmax-attention pooling + BN(eval) + linear + lsm.
// Phase 3 uses 4 independent accumulators per wave for load ILP.
// ---------------------------------------------------------------------------
__global__ __launch_bounds__(256) void pool_final(
    const float* __restrict__ h, const float* __restrict__ gate,
    const int* __restrict__ batch,
    const float* __restrict__ gamma_, const float* __restrict__ beta_,
    const float* __restrict__ mean_, const float* __restrict__ var_,
    const float* __restrict__ Wl, const float* __restrict__ bl,
    float* __restrict__ out, int N)
{
    int g = blockIdx.x;
    int tid = threadIdx.x;

    int lo = 0, hi = N;
    while (lo < hi) { int mid = (lo + hi) >> 1; if (batch[mid] < g) lo = mid + 1; else hi = mid; }
    int start = lo;
    hi = N;
    while (lo < hi) { int mid = (lo + hi) >> 1; if (batch[mid] < g + 1) lo = mid + 1; else hi = mid; }
    int end = lo;

    __shared__ float red[4];
    __shared__ float pool_s[4 * 64];

    int lane = tid & 63;
    int wave = tid >> 6;

    // segment max of gate
    float m = -FLT_MAX;
    for (int i = start + tid; i < end; i += 256) m = fmaxf(m, gate[i]);
    #pragma unroll
    for (int off = 32; off; off >>= 1) m = fmaxf(m, __shfl_xor(m, off));
    if (lane == 0) red[wave] = m;
    __syncthreads();
    m = fmaxf(fmaxf(red[0], red[1]), fmaxf(red[2], red[3]));
    __syncthreads();

    // segment sum of exp
    float s = 0.f;
    for (int i = start + tid; i < end; i += 256) s += expf(gate[i] - m);
    #pragma unroll
    for (int off = 32; off; off >>= 1) s += __shfl_xor(s, off);
    if (lane == 0) red[wave] = s;
    __syncthreads();
    s = red[0] + red[1] + red[2] + red[3];

    // weighted feature sum, 4 accumulators per wave (rows wave, wave+4, ...)
    float a0 = 0.f, a1 = 0.f, a2 = 0.f, a3 = 0.f;
    int i = start + wave;
    for (; i + 12 < end; i += 16) {
        float e0 = expf(gate[i]      - m);
        float e1 = expf(gate[i + 4]  - m);
        float e2 = expf(gate[i + 8]  - m);
        float e3 = expf(gate[i + 12] - m);
        float t0 = h[(size_t)(i)      * 64 + lane];
        float t1 = h[(size_t)(i + 4)  * 64 + lane];
        float t2 = h[(size_t)(i + 8)  * 64 + lane];
        float t3 = h[(size_t)(i + 12) * 64 + lane];
        a0 = fmaf(e0, t0, a0);
        a1 = fmaf(e1, t1, a1);
        a2 = fmaf(e2, t2, a2);
        a3 = fmaf(e3, t3, a3);
    }
    for (; i < end; i += 4) {
        float e = expf(gate[i] - m);
        a0 = fmaf(e, h[(size_t)i * 64 + lane], a0);
    }
    pool_s[wave * 64 + lane] = (a0 + a1) + (a2 + a3);
    __syncthreads();

    // BN + linear(64x2) + log_softmax
    if (wave == 0) {
        float p = pool_s[lane] + pool_s[64 + lane] + pool_s[128 + lane] + pool_s[192 + lane];
        p = (end > start) ? (p / s) : 0.f;
        float nrm = (p - mean_[lane]) / sqrtf(var_[lane] + BN_EPS) * gamma_[lane] + beta_[lane];
        float l0 = nrm * Wl[lane * 2 + 0];
        float l1 = nrm * Wl[lane * 2 + 1];
        #pragma unroll
        for (int off = 32; off; off >>= 1) {
            l0 += __shfl_xor(l0, off);
            l1 += __shfl_xor(l1, off);
        }
        if (lane == 0) {
            l0 += bl[0];
            l1 += bl[1];
            float mx = fmaxf(l0, l1);
            float lse = mx + logf(expf(l0 - mx) + expf(l1 - mx));
            out[g * 2 + 0] = l0 - lse;
            out[g * 2 + 1] = l1 - lse;
        }
    }
}

// ---------------------------------------------------------------------------
extern "C" void kernel_launch(void* const* d_in, const int* in_sizes, int n_in,
                              void* d_out, int out_size, void* d_ws, size_t ws_size,
                              hipStream_t stream)
{
    const float* x     = (const float*)d_in[0];
    const int*   eidx  = (const int*)d_in[1];   // [2, E]: row0=src, row1=dst
    const int*   batch = (const int*)d_in[2];
    const float* W1    = (const float*)d_in[3];
    const float* b1    = (const float*)d_in[4];
    const float* W2    = (const float*)d_in[5];
    const float* b2    = (const float*)d_in[6];
    const float* Wg    = (const float*)d_in[7];
    const float* bg    = (const float*)d_in[8];
    const float* bng   = (const float*)d_in[9];
    const float* bnb   = (const float*)d_in[10];
    const float* bnm   = (const float*)d_in[11];
    const float* bnv   = (const float*)d_in[12];
    const float* Wl    = (const float*)d_in[13];
    const float* bl    = (const float*)d_in[14];
    float* out = (float*)d_out;

    int N = in_sizes[0] / 64;
    int E = in_sizes[1] / 2;
    int G = out_size / 2;
    int NB = (N + 255) / 256;   // scan blocks (<= 512 required)

    char* w = (char*)d_ws;
    float* h        = (float*)w;                 w += (size_t)N * 64 * sizeof(float);
    float* gate     = (float*)w;                 w += (size_t)N * sizeof(float);
    int*   deg      = (int*)w;                   w += (size_t)N * sizeof(int);
    int*   excl     = (int*)w;                   w += (size_t)N * sizeof(int);
    int*   row_start= (int*)w;                   w += (size_t)(N + 1) * sizeof(int);
    int*   cursor   = (int*)w;                   w += (size_t)N * sizeof(int);
    int*   bsum     = (int*)w;                   w += (size_t)512 * sizeof(int);
    int*   eord     = (int*)w;                   // E ints

    const int* src = eidx;
    const int* dst = eidx + E;

    hipMemsetAsync(deg, 0, (size_t)N * sizeof(int), stream);

    int EB4 = (E + 1023) / 1024;  // 4 edges per thread
    deg_hist  <<<EB4, 256, 0, stream>>>(dst, deg, E);
    scan_block<<<NB, 256, 0, stream>>>(deg, excl, bsum, N);
    scan_tops <<<1, 512, 0, stream>>>(bsum, NB);
    scan_add  <<<NB, 256, 0, stream>>>(excl, bsum, row_start, cursor, N, E);
    edge_place<<<EB4, 256, 0, stream>>>(src, dst, cursor, eord, E);

    fused_mlp <<<1024, 256, 0, stream>>>(x, eord, row_start, W1, b1, W2, b2,
                                         Wg, bg, h, gate, N);

    pool_final<<<G, 256, 0, stream>>>(h, gate, batch, bng, bnb, bnm, bnv,
                                      Wl, bl, out, N);
}

// Round 5
// 395.539 us; speedup vs baseline: 1.5454x; 1.2400x over previous
//
#include <hip/hip_runtime.h>
#include <math.h>
#include <float.h>

#define BN_EPS 1e-5f

typedef short s16x8 __attribute__((ext_vector_type(8)));
typedef float f32x4 __attribute__((ext_vector_type(4)));

__device__ __forceinline__ unsigned short f2bf(float f) {
    unsigned u = __float_as_uint(f);
    u += 0x7FFFu + ((u >> 16) & 1u);          // round-to-nearest-even
    return (unsigned short)(u >> 16);
}
__device__ __forceinline__ float bf2f(unsigned short b) {
    return __uint_as_float(((unsigned)b) << 16);
}

// ---------------------------------------------------------------------------
// Kernel 1: in-degree histogram (4 edges/thread)
// ---------------------------------------------------------------------------
__global__ __launch_bounds__(256) void deg_hist(
    const int* __restrict__ dst, int* deg, int E)
{
    int base = (blockIdx.x * 256 + threadIdx.x) * 4;
    if (base + 3 < E) {
        int4 d = *(const int4*)(dst + base);
        atomicAdd(&deg[d.x], 1);
        atomicAdd(&deg[d.y], 1);
        atomicAdd(&deg[d.z], 1);
        atomicAdd(&deg[d.w], 1);
    } else {
        for (int e = base; e < E; ++e) atomicAdd(&deg[dst[e]], 1);
    }
}

// ---------------------------------------------------------------------------
// Kernel 2a: per-block exclusive scan of deg (256/block), write block sums
// ---------------------------------------------------------------------------
__global__ __launch_bounds__(256) void scan_block(
    const int* __restrict__ deg, int* __restrict__ excl,
    int* __restrict__ bsum, int N)
{
    int tid = threadIdx.x;
    int i = blockIdx.x * 256 + tid;
    int lane = tid & 63, wave = tid >> 6;
    int orig = (i < N) ? deg[i] : 0;
    int v = orig;
    #pragma unroll
    for (int d = 1; d < 64; d <<= 1) {
        int t = __shfl_up(v, d);
        if (lane >= d) v += t;
    }
    __shared__ int ws[4];
    if (lane == 63) ws[wave] = v;
    __syncthreads();
    int woff = 0;
    for (int w = 0; w < wave; ++w) woff += ws[w];
    int incl = v + woff;
    if (i < N) excl[i] = incl - orig;
    if (tid == 255) bsum[blockIdx.x] = incl;
}

// ---------------------------------------------------------------------------
// Kernel 2b: scan the block sums (NB <= 512), in place -> exclusive offsets
// ---------------------------------------------------------------------------
__global__ __launch_bounds__(512) void scan_tops(int* bsum, int NB)
{
    __shared__ int s[512];
    int tid = threadIdx.x;
    int v = (tid < NB) ? bsum[tid] : 0;
    s[tid] = v;
    __syncthreads();
    for (int d = 1; d < 512; d <<= 1) {
        int t = (tid >= d) ? s[tid - d] : 0;
        __syncthreads();
        s[tid] += t;
        __syncthreads();
    }
    if (tid < NB) bsum[tid] = s[tid] - v;   // exclusive
}

// ---------------------------------------------------------------------------
// Kernel 2c: combine -> row_start[i], cursor[i]; row_start[N] = E
// ---------------------------------------------------------------------------
__global__ __launch_bounds__(256) void scan_add(
    const int* __restrict__ excl, const int* __restrict__ bsum,
    int* __restrict__ row_start, int* __restrict__ cursor, int N, int E)
{
    int i = blockIdx.x * 256 + threadIdx.x;
    if (i < N) {
        int r = excl[i] + bsum[i >> 8];
        row_start[i] = r;
        cursor[i] = r;
    }
    if (i == 0) row_start[N] = E;
}

// ---------------------------------------------------------------------------
// Kernel 3: place edge src ids into CSR slots (counting-sort scatter)
// ---------------------------------------------------------------------------
__global__ __launch_bounds__(256) void edge_place(
    const int* __restrict__ src, const int* __restrict__ dst,
    int* cursor, int* __restrict__ eord, int E)
{
    int base = (blockIdx.x * 256 + threadIdx.x) * 4;
    if (base + 3 < E) {
        int4 d = *(const int4*)(dst + base);
        int4 s = *(const int4*)(src + base);
        eord[atomicAdd(&cursor[d.x], 1)] = s.x;
        eord[atomicAdd(&cursor[d.y], 1)] = s.y;
        eord[atomicAdd(&cursor[d.z], 1)] = s.z;
        eord[atomicAdd(&cursor[d.w], 1)] = s.w;
    } else {
        for (int e = base; e < E; ++e)
            eord[atomicAdd(&cursor[dst[e]], 1)] = src[e];
    }
}

// ---------------------------------------------------------------------------
// Kernel 4: gather only.  v[i] = x[i] + sum_{j->i} x[j], stored bf16.
// Wave per node, 8 independent accumulators, no LDS -> full occupancy.
// ---------------------------------------------------------------------------
__global__ __launch_bounds__(256) void gather_v(
    const float* __restrict__ x,
    const int* __restrict__ eord, const int* __restrict__ row_start,
    unsigned short* __restrict__ v_out, int N)
{
    int lane = threadIdx.x & 63;
    int wave = threadIdx.x >> 6;
    int stride = gridDim.x * 4;

    for (int node = blockIdx.x * 4 + wave; node < N; node += stride) {
        size_t row = (size_t)node * 64;
        int beg = row_start[node];
        int end = row_start[node + 1];

        float v0 = x[row + lane];
        float v1 = 0.f, v2 = 0.f, v3 = 0.f, v4 = 0.f, v5 = 0.f, v6 = 0.f, v7 = 0.f;

        for (int base = beg; base < end; base += 64) {
            int ei = (base + lane < end) ? eord[base + lane] : 0;
            int cnt = end - base; if (cnt > 64) cnt = 64;
            int j = 0;
            for (; j + 8 <= cnt; j += 8) {
                int s0 = __builtin_amdgcn_readlane(ei, j + 0);
                int s1 = __builtin_amdgcn_readlane(ei, j + 1);
                int s2 = __builtin_amdgcn_readlane(ei, j + 2);
                int s3 = __builtin_amdgcn_readlane(ei, j + 3);
                int s4 = __builtin_amdgcn_readlane(ei, j + 4);
                int s5 = __builtin_amdgcn_readlane(ei, j + 5);
                int s6 = __builtin_amdgcn_readlane(ei, j + 6);
                int s7 = __builtin_amdgcn_readlane(ei, j + 7);
                float t0 = x[(size_t)s0 * 64 + lane];
                float t1 = x[(size_t)s1 * 64 + lane];
                float t2 = x[(size_t)s2 * 64 + lane];
                float t3 = x[(size_t)s3 * 64 + lane];
                float t4 = x[(size_t)s4 * 64 + lane];
                float t5 = x[(size_t)s5 * 64 + lane];
                float t6 = x[(size_t)s6 * 64 + lane];
                float t7 = x[(size_t)s7 * 64 + lane];
                v0 += t0; v1 += t1; v2 += t2; v3 += t3;
                v4 += t4; v5 += t5; v6 += t6; v7 += t7;
            }
            for (; j < cnt; ++j) {
                int s = __builtin_amdgcn_readlane(ei, j);
                v1 += x[(size_t)s * 64 + lane];
            }
        }
        float v = ((v0 + v1) + (v2 + v3)) + ((v4 + v5) + (v6 + v7));
        v_out[row + lane] = f2bf(v);
    }
}

// ---------------------------------------------------------------------------
// Kernel 5: MFMA MLP.  Each wave computes 16 nodes:
//   h = relu(relu(v@W1+b1)@W2+b2); gate = h@Wg+bg
// A-frags (A[m=lane&15][k=quad*8+j]) straight from global bf16 v;
// layer1->layer2 via LDS C-layout->A-layout round trip (row pad 72 to
// break the 128B-stride b128 bank conflict).  Same-wave LDS only: no
// __syncthreads needed (DS pipe is in-order per wave).
// ---------------------------------------------------------------------------
__global__ __launch_bounds__(256) void mlp_mfma(
    const unsigned short* __restrict__ v,
    const float* __restrict__ W1, const float* __restrict__ b1,
    const float* __restrict__ W2, const float* __restrict__ b2,
    const float* __restrict__ Wg, const float* __restrict__ bg,
    unsigned short* __restrict__ h_out, float* __restrict__ gate_out, int N)
{
    int lane = threadIdx.x & 63;
    int wave = threadIdx.x >> 6;
    int quad = lane >> 4;
    int col  = lane & 15;

    // B-frags in registers: B[k=kh*32+quad*8+j][n=nt*16+col]
    s16x8 w1f[4][2], w2f[4][2];
    #pragma unroll
    for (int nt = 0; nt < 4; ++nt)
        #pragma unroll
        for (int kh = 0; kh < 2; ++kh) {
            s16x8 f1, f2;
            #pragma unroll
            for (int j = 0; j < 8; ++j) {
                int k = kh * 32 + quad * 8 + j;
                f1[j] = (short)f2bf(W1[k * 64 + nt * 16 + col]);
                f2[j] = (short)f2bf(W2[k * 64 + nt * 16 + col]);
            }
            w1f[nt][kh] = f1; w2f[nt][kh] = f2;
        }
    float b1v[4], b2v[4], wgv[4];
    #pragma unroll
    for (int nt = 0; nt < 4; ++nt) {
        b1v[nt] = b1[nt * 16 + col];
        b2v[nt] = b2[nt * 16 + col];
        wgv[nt] = Wg[nt * 16 + col];
    }
    float bgv = bg[0];

    __shared__ unsigned short h1s[4][16][72];   // row pad 64->72: no conflicts
    unsigned short (*tile)[72] = h1s[wave];

    int base = blockIdx.x * 64 + wave * 16;     // 16 nodes per wave

    // layer-1 A-frags straight from global v (16B aligned)
    const unsigned short* vrow = v + (size_t)(base + col) * 64;
    s16x8 a0 = *(const s16x8*)(vrow + quad * 8);
    s16x8 a1 = *(const s16x8*)(vrow + 32 + quad * 8);

    f32x4 acc[4];
    #pragma unroll
    for (int nt = 0; nt < 4; ++nt) {
        f32x4 c = {0.f, 0.f, 0.f, 0.f};
        c = __builtin_amdgcn_mfma_f32_16x16x32_bf16(a0, w1f[nt][0], c, 0, 0, 0);
        c = __builtin_amdgcn_mfma_f32_16x16x32_bf16(a1, w1f[nt][1], c, 0, 0, 0);
        acc[nt] = c;
    }

    // epilogue 1: +b1, relu, write C-layout -> LDS tile (node-major)
    #pragma unroll
    for (int nt = 0; nt < 4; ++nt)
        #pragma unroll
        for (int r = 0; r < 4; ++r) {
            float hv = fmaxf(acc[nt][r] + b1v[nt], 0.f);
            tile[quad * 4 + r][nt * 16 + col] = f2bf(hv);
        }

    // layer-2 A-frags from LDS (same wave -> in-order DS, no barrier)
    s16x8 g0 = *(const s16x8*)&tile[col][quad * 8];
    s16x8 g1 = *(const s16x8*)&tile[col][32 + quad * 8];

    f32x4 acc2[4];
    #pragma unroll
    for (int nt = 0; nt < 4; ++nt) {
        f32x4 c = {0.f, 0.f, 0.f, 0.f};
        c = __builtin_amdgcn_mfma_f32_16x16x32_bf16(g0, w2f[nt][0], c, 0, 0, 0);
        c = __builtin_amdgcn_mfma_f32_16x16x32_bf16(g1, w2f[nt][1], c, 0, 0, 0);
        acc2[nt] = c;
    }

    // epilogue 2: +b2, relu, store h (bf16), fold gate partials
    float gp[4] = {0.f, 0.f, 0.f, 0.f};
    #pragma unroll
    for (int nt = 0; nt < 4; ++nt)
        #pragma unroll
        for (int r = 0; r < 4; ++r) {
            float hv = fmaxf(acc2[nt][r] + b2v[nt], 0.f);
            h_out[(size_t)(base + quad * 4 + r) * 64 + nt * 16 + col] = f2bf(hv);
            gp[r] = fmaf(hv, wgv[nt], gp[r]);
        }
    #pragma unroll
    for (int r = 0; r < 4; ++r) {
        float t = gp[r];
        t += __shfl_xor(t, 1);
        t += __shfl_xor(t, 2);
        t += __shfl_xor(t, 4);
        t += __shfl_xor(t, 8);
        int node = base + quad * 4 + r;
        if (col == 0 && node < N) gate_out[node] = t + bgv;
    }
}

// ---------------------------------------------------------------------------
// Kernel 6: per-graph softmax-attention pooling + BN(eval) + linear + lsm.
// ---------------------------------------------------------------------------
__global__ __launch_bounds__(256) void pool_final(
    const unsigned short* __restrict__ h, const float* __restrict__ gate,
    const int* __restrict__ batch,
    const float* __restrict__ gamma_, const float* __restrict__ beta_,
    const float* __restrict__ mean_, const float* __restrict__ var_,
    const float* __restrict__ Wl, const float* __restrict__ bl,
    float* __restrict__ out, int N)
{
    int g = blockIdx.x;
    int tid = threadIdx.x;

    int lo = 0, hi = N;
    while (lo < hi) { int mid = (lo + hi) >> 1; if (batch[mid] < g) lo = mid + 1; else hi = mid; }
    int start = lo;
    hi = N;
    while (lo < hi) { int mid = (lo + hi) >> 1; if (batch[mid] < g + 1) lo = mid + 1; else hi = mid; }
    int end = lo;

    __shared__ float red[4];
    __shared__ float pool_s[4 * 64];

    int lane = tid & 63;
    int wave = tid >> 6;

    float m = -FLT_MAX;
    for (int i = start + tid; i < end; i += 256) m = fmaxf(m, gate[i]);
    #pragma unroll
    for (int off = 32; off; off >>= 1) m = fmaxf(m, __shfl_xor(m, off));
    if (lane == 0) red[wave] = m;
    __syncthreads();
    m = fmaxf(fmaxf(red[0], red[1]), fmaxf(red[2], red[3]));
    __syncthreads();

    float s = 0.f;
    for (int i = start + tid; i < end; i += 256) s += expf(gate[i] - m);
    #pragma unroll
    for (int off = 32; off; off >>= 1) s += __shfl_xor(s, off);
    if (lane == 0) red[wave] = s;
    __syncthreads();
    s = red[0] + red[1] + red[2] + red[3];

    float a0 = 0.f, a1 = 0.f, a2 = 0.f, a3 = 0.f;
    int i = start + wave;
    for (; i + 12 < end; i += 16) {
        float e0 = expf(gate[i]      - m);
        float e1 = expf(gate[i + 4]  - m);
        float e2 = expf(gate[i + 8]  - m);
        float e3 = expf(gate[i + 12] - m);
        float t0 = bf2f(h[(size_t)(i)      * 64 + lane]);
        float t1 = bf2f(h[(size_t)(i + 4)  * 64 + lane]);
        float t2 = bf2f(h[(size_t)(i + 8)  * 64 + lane]);
        float t3 = bf2f(h[(size_t)(i + 12) * 64 + lane]);
        a0 = fmaf(e0, t0, a0);
        a1 = fmaf(e1, t1, a1);
        a2 = fmaf(e2, t2, a2);
        a3 = fmaf(e3, t3, a3);
    }
    for (; i < end; i += 4) {
        float e = expf(gate[i] - m);
        a0 = fmaf(e, bf2f(h[(size_t)i * 64 + lane]), a0);
    }
    pool_s[wave * 64 + lane] = (a0 + a1) + (a2 + a3);
    __syncthreads();

    if (wave == 0) {
        float p = pool_s[lane] + pool_s[64 + lane] + pool_s[128 + lane] + pool_s[192 + lane];
        p = (end > start) ? (p / s) : 0.f;
        float nrm = (p - mean_[lane]) / sqrtf(var_[lane] + BN_EPS) * gamma_[lane] + beta_[lane];
        float l0 = nrm * Wl[lane * 2 + 0];
        float l1 = nrm * Wl[lane * 2 + 1];
        #pragma unroll
        for (int off = 32; off; off >>= 1) {
            l0 += __shfl_xor(l0, off);
            l1 += __shfl_xor(l1, off);
        }
        if (lane == 0) {
            l0 += bl[0];
            l1 += bl[1];
            float mx = fmaxf(l0, l1);
            float lse = mx + logf(expf(l0 - mx) + expf(l1 - mx));
            out[g * 2 + 0] = l0 - lse;
            out[g * 2 + 1] = l1 - lse;
        }
    }
}

// ---------------------------------------------------------------------------
extern "C" void kernel_launch(void* const* d_in, const int* in_sizes, int n_in,
                              void* d_out, int out_size, void* d_ws, size_t ws_size,
                              hipStream_t stream)
{
    const float* x     = (const float*)d_in[0];
    const int*   eidx  = (const int*)d_in[1];   // [2, E]: row0=src, row1=dst
    const int*   batch = (const int*)d_in[2];
    const float* W1    = (const float*)d_in[3];
    const float* b1    = (const float*)d_in[4];
    const float* W2    = (const float*)d_in[5];
    const float* b2    = (const float*)d_in[6];
    const float* Wg    = (const float*)d_in[7];
    const float* bg    = (const float*)d_in[8];
    const float* bng   = (const float*)d_in[9];
    const float* bnb   = (const float*)d_in[10];
    const float* bnm   = (const float*)d_in[11];
    const float* bnv   = (const float*)d_in[12];
    const float* Wl    = (const float*)d_in[13];
    const float* bl    = (const float*)d_in[14];
    float* out = (float*)d_out;

    int N = in_sizes[0] / 64;
    int E = in_sizes[1] / 2;
    int G = out_size / 2;
    int NB = (N + 255) / 256;        // scan blocks (<= 512 required)
    int NP = ((N + 63) / 64) * 64;   // padded node count (64-node MLP tiles)

    char* w = (char*)d_ws;
    unsigned short* v    = (unsigned short*)w;   w += (size_t)NP * 64 * sizeof(unsigned short);
    unsigned short* h    = (unsigned short*)w;   w += (size_t)NP * 64 * sizeof(unsigned short);
    float* gate     = (float*)w;                 w += (size_t)N * sizeof(float);
    int*   deg      = (int*)w;                   w += (size_t)N * sizeof(int);
    int*   excl     = (int*)w;                   w += (size_t)N * sizeof(int);
    int*   row_start= (int*)w;                   w += (size_t)(N + 1) * sizeof(int);
    int*   cursor   = (int*)w;                   w += (size_t)N * sizeof(int);
    int*   bsum     = (int*)w;                   w += (size_t)512 * sizeof(int);
    int*   eord     = (int*)w;                   // E ints

    const int* src = eidx;
    const int* dst = eidx + E;

    hipMemsetAsync(deg, 0, (size_t)N * sizeof(int), stream);

    int EB4 = (E + 1023) / 1024;  // 4 edges per thread
    deg_hist  <<<EB4, 256, 0, stream>>>(dst, deg, E);
    scan_block<<<NB, 256, 0, stream>>>(deg, excl, bsum, N);
    scan_tops <<<1, 512, 0, stream>>>(bsum, NB);
    scan_add  <<<NB, 256, 0, stream>>>(excl, bsum, row_start, cursor, N, E);
    edge_place<<<EB4, 256, 0, stream>>>(src, dst, cursor, eord, E);

    gather_v  <<<2048, 256, 0, stream>>>(x, eord, row_start, v, N);

    mlp_mfma  <<<NP / 64, 256, 0, stream>>>(v, W1, b1, W2, b2, Wg, bg,
                                            h, gate, N);

    pool_final<<<G, 256, 0, stream>>>(h, gate, batch, bng, bnb, bnm, bnv,
                                      Wl, bl, out, N);
}

// Round 6
// 381.590 us; speedup vs baseline: 1.6019x; 1.0366x over previous
//
#include <hip/hip_runtime.h>
#include <math.h>
#include <float.h>

#define BN_EPS 1e-5f

typedef short s16x8 __attribute__((ext_vector_type(8)));
typedef float f32x4 __attribute__((ext_vector_type(4)));

__device__ __forceinline__ unsigned short f2bf(float f) {
    unsigned u = __float_as_uint(f);
    u += 0x7FFFu + ((u >> 16) & 1u);          // round-to-nearest-even
    return (unsigned short)(u >> 16);
}
__device__ __forceinline__ float bf2f(unsigned short b) {
    return __uint_as_float(((unsigned)b) << 16);
}

// ---------------------------------------------------------------------------
// Kernel 0: x (fp32) -> xb (bf16), elementwise, vectorized
// ---------------------------------------------------------------------------
__global__ __launch_bounds__(256) void cvt_bf16(
    const float* __restrict__ x, unsigned short* __restrict__ xb, int n4)
{
    int i = blockIdx.x * 256 + threadIdx.x;
    if (i < n4) {
        float4 f = *(const float4*)(x + (size_t)i * 4);
        ushort4 o;
        o.x = f2bf(f.x); o.y = f2bf(f.y); o.z = f2bf(f.z); o.w = f2bf(f.w);
        *(ushort4*)(xb + (size_t)i * 4) = o;
    }
}

// ---------------------------------------------------------------------------
// Kernel 1: in-degree histogram (8 edges/thread, 8 outstanding atomics)
// ---------------------------------------------------------------------------
__global__ __launch_bounds__(256) void deg_hist(
    const int* __restrict__ dst, int* deg, int E)
{
    int base = (blockIdx.x * 256 + threadIdx.x) * 8;
    if (base + 7 < E) {
        int4 d0 = *(const int4*)(dst + base);
        int4 d1 = *(const int4*)(dst + base + 4);
        atomicAdd(&deg[d0.x], 1);
        atomicAdd(&deg[d0.y], 1);
        atomicAdd(&deg[d0.z], 1);
        atomicAdd(&deg[d0.w], 1);
        atomicAdd(&deg[d1.x], 1);
        atomicAdd(&deg[d1.y], 1);
        atomicAdd(&deg[d1.z], 1);
        atomicAdd(&deg[d1.w], 1);
    } else {
        for (int e = base; e < E; ++e) atomicAdd(&deg[dst[e]], 1);
    }
}

// ---------------------------------------------------------------------------
// Kernel 2a: per-block exclusive scan of deg (256/block), write block sums
// ---------------------------------------------------------------------------
__global__ __launch_bounds__(256) void scan_block(
    const int* __restrict__ deg, int* __restrict__ excl,
    int* __restrict__ bsum, int N)
{
    int tid = threadIdx.x;
    int i = blockIdx.x * 256 + tid;
    int lane = tid & 63, wave = tid >> 6;
    int orig = (i < N) ? deg[i] : 0;
    int v = orig;
    #pragma unroll
    for (int d = 1; d < 64; d <<= 1) {
        int t = __shfl_up(v, d);
        if (lane >= d) v += t;
    }
    __shared__ int ws[4];
    if (lane == 63) ws[wave] = v;
    __syncthreads();
    int woff = 0;
    for (int w = 0; w < wave; ++w) woff += ws[w];
    int incl = v + woff;
    if (i < N) excl[i] = incl - orig;
    if (tid == 255) bsum[blockIdx.x] = incl;
}

// ---------------------------------------------------------------------------
// Kernel 2b: scan the block sums (NB <= 512), in place -> exclusive offsets
// ---------------------------------------------------------------------------
__global__ __launch_bounds__(512) void scan_tops(int* bsum, int NB)
{
    __shared__ int s[512];
    int tid = threadIdx.x;
    int v = (tid < NB) ? bsum[tid] : 0;
    s[tid] = v;
    __syncthreads();
    for (int d = 1; d < 512; d <<= 1) {
        int t = (tid >= d) ? s[tid - d] : 0;
        __syncthreads();
        s[tid] += t;
        __syncthreads();
    }
    if (tid < NB) bsum[tid] = s[tid] - v;   // exclusive
}

// ---------------------------------------------------------------------------
// Kernel 2c: combine -> row_start[i], cursor[i]; row_start[N] = E
// ---------------------------------------------------------------------------
__global__ __launch_bounds__(256) void scan_add(
    const int* __restrict__ excl, const int* __restrict__ bsum,
    int* __restrict__ row_start, int* __restrict__ cursor, int N, int E)
{
    int i = blockIdx.x * 256 + threadIdx.x;
    if (i < N) {
        int r = excl[i] + bsum[i >> 8];
        row_start[i] = r;
        cursor[i] = r;
    }
    if (i == 0) row_start[N] = E;
}

// ---------------------------------------------------------------------------
// Kernel 3: place edge src ids into CSR slots.  8 edges/thread; all 8
// atomics issued before the 8 dependent scattered stores (8 chains in
// flight).  WRITE amplification (~64B/line per 4B store) is structural.
// ---------------------------------------------------------------------------
__global__ __launch_bounds__(256) void edge_place(
    const int* __restrict__ src, const int* __restrict__ dst,
    int* cursor, int* __restrict__ eord, int E)
{
    int base = (blockIdx.x * 256 + threadIdx.x) * 8;
    if (base + 7 < E) {
        int4 d0 = *(const int4*)(dst + base);
        int4 d1 = *(const int4*)(dst + base + 4);
        int4 s0 = *(const int4*)(src + base);
        int4 s1 = *(const int4*)(src + base + 4);
        int p0 = atomicAdd(&cursor[d0.x], 1);
        int p1 = atomicAdd(&cursor[d0.y], 1);
        int p2 = atomicAdd(&cursor[d0.z], 1);
        int p3 = atomicAdd(&cursor[d0.w], 1);
        int p4 = atomicAdd(&cursor[d1.x], 1);
        int p5 = atomicAdd(&cursor[d1.y], 1);
        int p6 = atomicAdd(&cursor[d1.z], 1);
        int p7 = atomicAdd(&cursor[d1.w], 1);
        eord[p0] = s0.x;
        eord[p1] = s0.y;
        eord[p2] = s0.z;
        eord[p3] = s0.w;
        eord[p4] = s1.x;
        eord[p5] = s1.y;
        eord[p6] = s1.z;
        eord[p7] = s1.w;
    } else {
        for (int e = base; e < E; ++e)
            eord[atomicAdd(&cursor[dst[e]], 1)] = src[e];
    }
}

// ---------------------------------------------------------------------------
// Kernel 4: gather.  v[i] = x[i] + sum_{j->i} xb[j]  (neighbors read as
// bf16 -> half the random-gather line traffic; fp32 accumulate; self term
// fp32 exact).  Wave per node, 8 independent accumulators, no LDS.
// ---------------------------------------------------------------------------
__global__ __launch_bounds__(256) void gather_v(
    const float* __restrict__ x, const unsigned short* __restrict__ xb,
    const int* __restrict__ eord, const int* __restrict__ row_start,
    unsigned short* __restrict__ v_out, int N)
{
    int lane = threadIdx.x & 63;
    int wave = threadIdx.x >> 6;
    int stride = gridDim.x * 4;

    for (int node = blockIdx.x * 4 + wave; node < N; node += stride) {
        size_t row = (size_t)node * 64;
        int beg = row_start[node];
        int end = row_start[node + 1];

        float v0 = x[row + lane];
        float v1 = 0.f, v2 = 0.f, v3 = 0.f, v4 = 0.f, v5 = 0.f, v6 = 0.f, v7 = 0.f;

        for (int base = beg; base < end; base += 64) {
            int ei = (base + lane < end) ? eord[base + lane] : 0;
            int cnt = end - base; if (cnt > 64) cnt = 64;
            int j = 0;
            for (; j + 8 <= cnt; j += 8) {
                int s0 = __builtin_amdgcn_readlane(ei, j + 0);
                int s1 = __builtin_amdgcn_readlane(ei, j + 1);
                int s2 = __builtin_amdgcn_readlane(ei, j + 2);
                int s3 = __builtin_amdgcn_readlane(ei, j + 3);
                int s4 = __builtin_amdgcn_readlane(ei, j + 4);
                int s5 = __builtin_amdgcn_readlane(ei, j + 5);
                int s6 = __builtin_amdgcn_readlane(ei, j + 6);
                int s7 = __builtin_amdgcn_readlane(ei, j + 7);
                unsigned short t0 = xb[(size_t)s0 * 64 + lane];
                unsigned short t1 = xb[(size_t)s1 * 64 + lane];
                unsigned short t2 = xb[(size_t)s2 * 64 + lane];
                unsigned short t3 = xb[(size_t)s3 * 64 + lane];
                unsigned short t4 = xb[(size_t)s4 * 64 + lane];
                unsigned short t5 = xb[(size_t)s5 * 64 + lane];
                unsigned short t6 = xb[(size_t)s6 * 64 + lane];
                unsigned short t7 = xb[(size_t)s7 * 64 + lane];
                v0 += bf2f(t0); v1 += bf2f(t1); v2 += bf2f(t2); v3 += bf2f(t3);
                v4 += bf2f(t4); v5 += bf2f(t5); v6 += bf2f(t6); v7 += bf2f(t7);
            }
            for (; j < cnt; ++j) {
                int s = __builtin_amdgcn_readlane(ei, j);
                v1 += bf2f(xb[(size_t)s * 64 + lane]);
            }
        }
        float v = ((v0 + v1) + (v2 + v3)) + ((v4 + v5) + (v6 + v7));
        v_out[row + lane] = f2bf(v);
    }
}

// ---------------------------------------------------------------------------
// Kernel 5: MFMA MLP.  Each wave computes 16 nodes (see R5 notes).
// ---------------------------------------------------------------------------
__global__ __launch_bounds__(256) void mlp_mfma(
    const unsigned short* __restrict__ v,
    const float* __restrict__ W1, const float* __restrict__ b1,
    const float* __restrict__ W2, const float* __restrict__ b2,
    const float* __restrict__ Wg, const float* __restrict__ bg,
    unsigned short* __restrict__ h_out, float* __restrict__ gate_out, int N)
{
    int lane = threadIdx.x & 63;
    int wave = threadIdx.x >> 6;
    int quad = lane >> 4;
    int col  = lane & 15;

    s16x8 w1f[4][2], w2f[4][2];
    #pragma unroll
    for (int nt = 0; nt < 4; ++nt)
        #pragma unroll
        for (int kh = 0; kh < 2; ++kh) {
            s16x8 f1, f2;
            #pragma unroll
            for (int j = 0; j < 8; ++j) {
                int k = kh * 32 + quad * 8 + j;
                f1[j] = (short)f2bf(W1[k * 64 + nt * 16 + col]);
                f2[j] = (short)f2bf(W2[k * 64 + nt * 16 + col]);
            }
            w1f[nt][kh] = f1; w2f[nt][kh] = f2;
        }
    float b1v[4], b2v[4], wgv[4];
    #pragma unroll
    for (int nt = 0; nt < 4; ++nt) {
        b1v[nt] = b1[nt * 16 + col];
        b2v[nt] = b2[nt * 16 + col];
        wgv[nt] = Wg[nt * 16 + col];
    }
    float bgv = bg[0];

    __shared__ unsigned short h1s[4][16][72];
    unsigned short (*tile)[72] = h1s[wave];

    int base = blockIdx.x * 64 + wave * 16;

    const unsigned short* vrow = v + (size_t)(base + col) * 64;
    s16x8 a0 = *(const s16x8*)(vrow + quad * 8);
    s16x8 a1 = *(const s16x8*)(vrow + 32 + quad * 8);

    f32x4 acc[4];
    #pragma unroll
    for (int nt = 0; nt < 4; ++nt) {
        f32x4 c = {0.f, 0.f, 0.f, 0.f};
        c = __builtin_amdgcn_mfma_f32_16x16x32_bf16(a0, w1f[nt][0], c, 0, 0, 0);
        c = __builtin_amdgcn_mfma_f32_16x16x32_bf16(a1, w1f[nt][1], c, 0, 0, 0);
        acc[nt] = c;
    }

    #pragma unroll
    for (int nt = 0; nt < 4; ++nt)
        #pragma unroll
        for (int r = 0; r < 4; ++r) {
            float hv = fmaxf(acc[nt][r] + b1v[nt], 0.f);
            tile[quad * 4 + r][nt * 16 + col] = f2bf(hv);
        }

    s16x8 g0 = *(const s16x8*)&tile[col][quad * 8];
    s16x8 g1 = *(const s16x8*)&tile[col][32 + quad * 8];

    f32x4 acc2[4];
    #pragma unroll
    for (int nt = 0; nt < 4; ++nt) {
        f32x4 c = {0.f, 0.f, 0.f, 0.f};
        c = __builtin_amdgcn_mfma_f32_16x16x32_bf16(g0, w2f[nt][0], c, 0, 0, 0);
        c = __builtin_amdgcn_mfma_f32_16x16x32_bf16(g1, w2f[nt][1], c, 0, 0, 0);
        acc2[nt] = c;
    }

    float gp[4] = {0.f, 0.f, 0.f, 0.f};
    #pragma unroll
    for (int nt = 0; nt < 4; ++nt)
        #pragma unroll
        for (int r = 0; r < 4; ++r) {
            float hv = fmaxf(acc2[nt][r] + b2v[nt], 0.f);
            h_out[(size_t)(base + quad * 4 + r) * 64 + nt * 16 + col] = f2bf(hv);
            gp[r] = fmaf(hv, wgv[nt], gp[r]);
        }
    #pragma unroll
    for (int r = 0; r < 4; ++r) {
        float t = gp[r];
        t += __shfl_xor(t, 1);
        t += __shfl_xor(t, 2);
        t += __shfl_xor(t, 4);
        t += __shfl_xor(t, 8);
        int node = base + quad * 4 + r;
        if (col == 0 && node < N) gate_out[node] = t + bgv;
    }
}

// ---------------------------------------------------------------------------
// Kernel 6: per-graph softmax-attention pooling + BN(eval) + linear + lsm.
// ---------------------------------------------------------------------------
__global__ __launch_bounds__(256) void pool_final(
    const unsigned short* __restrict__ h, const float* __restrict__ gate,
    const int* __restrict__ batch,
    const float* __restrict__ gamma_, const float* __restrict__ beta_,
    const float* __restrict__ mean_, const float* __restrict__ var_,
    const float* __restrict__ Wl, const float* __restrict__ bl,
    float* __restrict__ out, int N)
{
    int g = blockIdx.x;
    int tid = threadIdx.x;

    int lo = 0, hi = N;
    while (lo < hi) { int mid = (lo + hi) >> 1; if (batch[mid] < g) lo = mid + 1; else hi = mid; }
    int start = lo;
    hi = N;
    while (lo < hi) { int mid = (lo + hi) >> 1; if (batch[mid] < g + 1) lo = mid + 1; else hi = mid; }
    int end = lo;

    __shared__ float red[4];
    __shared__ float pool_s[4 * 64];

    int lane = tid & 63;
    int wave = tid >> 6;

    float m = -FLT_MAX;
    for (int i = start + tid; i < end; i += 256) m = fmaxf(m, gate[i]);
    #pragma unroll
    for (int off = 32; off; off >>= 1) m = fmaxf(m, __shfl_xor(m, off));
    if (lane == 0) red[wave] = m;
    __syncthreads();
    m = fmaxf(fmaxf(red[0], red[1]), fmaxf(red[2], red[3]));
    __syncthreads();

    float s = 0.f;
    for (int i = start + tid; i < end; i += 256) s += expf(gate[i] - m);
    #pragma unroll
    for (int off = 32; off; off >>= 1) s += __shfl_xor(s, off);
    if (lane == 0) red[wave] = s;
    __syncthreads();
    s = red[0] + red[1] + red[2] + red[3];

    float a0 = 0.f, a1 = 0.f, a2 = 0.f, a3 = 0.f;
    int i = start + wave;
    for (; i + 12 < end; i += 16) {
        float e0 = expf(gate[i]      - m);
        float e1 = expf(gate[i + 4]  - m);
        float e2 = expf(gate[i + 8]  - m);
        float e3 = expf(gate[i + 12] - m);
        float t0 = bf2f(h[(size_t)(i)      * 64 + lane]);
        float t1 = bf2f(h[(size_t)(i + 4)  * 64 + lane]);
        float t2 = bf2f(h[(size_t)(i + 8)  * 64 + lane]);
        float t3 = bf2f(h[(size_t)(i + 12) * 64 + lane]);
        a0 = fmaf(e0, t0, a0);
        a1 = fmaf(e1, t1, a1);
        a2 = fmaf(e2, t2, a2);
        a3 = fmaf(e3, t3, a3);
    }
    for (; i < end; i += 4) {
        float e = expf(gate[i] - m);
        a0 = fmaf(e, bf2f(h[(size_t)i * 64 + lane]), a0);
    }
    pool_s[wave * 64 + lane] = (a0 + a1) + (a2 + a3);
    __syncthreads();

    if (wave == 0) {
        float p = pool_s[lane] + pool_s[64 + lane] + pool_s[128 + lane] + pool_s[192 + lane];
        p = (end > start) ? (p / s) : 0.f;
        float nrm = (p - mean_[lane]) / sqrtf(var_[lane] + BN_EPS) * gamma_[lane] + beta_[lane];
        float l0 = nrm * Wl[lane * 2 + 0];
        float l1 = nrm * Wl[lane * 2 + 1];
        #pragma unroll
        for (int off = 32; off; off >>= 1) {
            l0 += __shfl_xor(l0, off);
            l1 += __shfl_xor(l1, off);
        }
        if (lane == 0) {
            l0 += bl[0];
            l1 += bl[1];
            float mx = fmaxf(l0, l1);
            float lse = mx + logf(expf(l0 - mx) + expf(l1 - mx));
            out[g * 2 + 0] = l0 - lse;
            out[g * 2 + 1] = l1 - lse;
        }
    }
}

// ---------------------------------------------------------------------------
extern "C" void kernel_launch(void* const* d_in, const int* in_sizes, int n_in,
                              void* d_out, int out_size, void* d_ws, size_t ws_size,
                              hipStream_t stream)
{
    const float* x     = (const float*)d_in[0];
    const int*   eidx  = (const int*)d_in[1];   // [2, E]: row0=src, row1=dst
    const int*   batch = (const int*)d_in[2];
    const float* W1    = (const float*)d_in[3];
    const float* b1    = (const float*)d_in[4];
    const float* W2    = (const float*)d_in[5];
    const float* b2    = (const float*)d_in[6];
    const float* Wg    = (const float*)d_in[7];
    const float* bg    = (const float*)d_in[8];
    const float* bng   = (const float*)d_in[9];
    const float* bnb   = (const float*)d_in[10];
    const float* bnm   = (const float*)d_in[11];
    const float* bnv   = (const float*)d_in[12];
    const float* Wl    = (const float*)d_in[13];
    const float* bl    = (const float*)d_in[14];
    float* out = (float*)d_out;

    int N = in_sizes[0] / 64;
    int E = in_sizes[1] / 2;
    int G = out_size / 2;
    int NB = (N + 255) / 256;        // scan blocks (<= 512 required)
    int NP = ((N + 63) / 64) * 64;   // padded node count (64-node MLP tiles)

    char* w = (char*)d_ws;
    unsigned short* v    = (unsigned short*)w;   w += (size_t)NP * 64 * sizeof(unsigned short);
    unsigned short* h    = (unsigned short*)w;   w += (size_t)NP * 64 * sizeof(unsigned short);
    float* gate     = (float*)w;                 w += (size_t)N * sizeof(float);
    int*   deg      = (int*)w;                   w += (size_t)N * sizeof(int);
    int*   excl     = (int*)w;                   w += (size_t)N * sizeof(int);
    int*   row_start= (int*)w;                   w += (size_t)(N + 1) * sizeof(int);
    int*   cursor   = (int*)w;                   w += (size_t)N * sizeof(int);
    int*   bsum     = (int*)w;                   w += (size_t)512 * sizeof(int);
    int*   eord     = (int*)w;                   // E ints

    unsigned short* xb = h;          // alias: xb dead before mlp_mfma writes h

    const int* src = eidx;
    const int* dst = eidx + E;

    hipMemsetAsync(deg, 0, (size_t)N * sizeof(int), stream);

    cvt_bf16  <<<(N * 64 / 4 + 255) / 256, 256, 0, stream>>>(x, xb, N * 64 / 4);

    int EB8 = (E + 2047) / 2048;  // 8 edges per thread
    deg_hist  <<<EB8, 256, 0, stream>>>(dst, deg, E);
    scan_block<<<NB, 256, 0, stream>>>(deg, excl, bsum, N);
    scan_tops <<<1, 512, 0, stream>>>(bsum, NB);
    scan_add  <<<NB, 256, 0, stream>>>(excl, bsum, row_start, cursor, N, E);
    edge_place<<<EB8, 256, 0, stream>>>(src, dst, cursor, eord, E);

    gather_v  <<<2048, 256, 0, stream>>>(x, xb, eord, row_start, v, N);

    mlp_mfma  <<<NP / 64, 256, 0, stream>>>(v, W1, b1, W2, b2, Wg, bg,
                                            h, gate, N);

    pool_final<<<G, 256, 0, stream>>>(h, gate, batch, bng, bnb, bnm, bnv,
                                      Wl, bl, out, N);
}

// Round 7
// 247.376 us; speedup vs baseline: 2.4711x; 1.5426x over previous
//
#include <hip/hip_runtime.h>
#include <math.h>
#include <float.h>

#define BN_EPS 1e-5f
#define PBLK 8192        // edges per partition block
#define CSR_CAP 12288    // LDS staging capacity per bucket (expected max ~8600)

typedef short s16x8 __attribute__((ext_vector_type(8)));
typedef float f32x4 __attribute__((ext_vector_type(4)));

__device__ __forceinline__ unsigned short f2bf(float f) {
    unsigned u = __float_as_uint(f);
    u += 0x7FFFu + ((u >> 16) & 1u);          // round-to-nearest-even
    return (unsigned short)(u >> 16);
}
__device__ __forceinline__ float bf2f(unsigned short b) {
    return __uint_as_float(((unsigned)b) << 16);
}

// ---------------------------------------------------------------------------
// Kernel 0: x (fp32) -> xb (bf16), elementwise, vectorized
// ---------------------------------------------------------------------------
__global__ __launch_bounds__(256) void cvt_bf16(
    const float* __restrict__ x, unsigned short* __restrict__ xb, int n4)
{
    int i = blockIdx.x * 256 + threadIdx.x;
    if (i < n4) {
        float4 f = *(const float4*)(x + (size_t)i * 4);
        ushort4 o;
        o.x = f2bf(f.x); o.y = f2bf(f.y); o.z = f2bf(f.z); o.w = f2bf(f.w);
        *(ushort4*)(xb + (size_t)i * 4) = o;
    }
}

// ---------------------------------------------------------------------------
// Kernel 1: coarse bucket histogram (bucket = dst>>9), LDS-aggregated:
// 256 global atomics per block instead of 2048 random ones.
// ---------------------------------------------------------------------------
__global__ __launch_bounds__(256) void bucket_hist(
    const int* __restrict__ dst, int* __restrict__ bcount, int E)
{
    __shared__ int hist[256];
    int tid = threadIdx.x;
    hist[tid] = 0;
    __syncthreads();

    int base = (blockIdx.x * 256 + tid) * 16;
    if (base + 15 < E) {
        #pragma unroll
        for (int q = 0; q < 4; ++q) {
            int4 d = *(const int4*)(dst + base + q * 4);
            atomicAdd(&hist[d.x >> 9], 1);
            atomicAdd(&hist[d.y >> 9], 1);
            atomicAdd(&hist[d.z >> 9], 1);
            atomicAdd(&hist[d.w >> 9], 1);
        }
    } else {
        for (int e = base; e < E; ++e) atomicAdd(&hist[dst[e] >> 9], 1);
    }
    __syncthreads();
    if (hist[tid]) atomicAdd(&bcount[tid], hist[tid]);
}

// ---------------------------------------------------------------------------
// Kernel 2: scan 256 bucket counts -> bbase[0..256] (exclusive), bcur = base
// ---------------------------------------------------------------------------
__global__ __launch_bounds__(64) void bucket_scan(
    const int* __restrict__ bcount, int* __restrict__ bbase, int* __restrict__ bcur)
{
    int lane = threadIdx.x;
    int carry = 0;
    for (int c = 0; c < 4; ++c) {
        int v = bcount[c * 64 + lane];
        int x = v;
        #pragma unroll
        for (int d = 1; d < 64; d <<= 1) { int t = __shfl_up(x, d); if (lane >= d) x += t; }
        int e = x - v + carry;
        bbase[c * 64 + lane] = e;
        bcur[c * 64 + lane] = e;
        carry += __shfl(x, 63);
    }
    if (lane == 0) bbase[256] = carry;
}

// ---------------------------------------------------------------------------
// Kernel 3: partition edges into bucket-contiguous packed form.
// Per block: LDS-sort PBLK edges by bucket, reserve one global chunk per
// bucket (1 atomic), write ~128B contiguous runs.  val = (dst&511)<<17 | src
// (requires N < 131072).
// ---------------------------------------------------------------------------
__global__ __launch_bounds__(256) void partition_edges(
    const int* __restrict__ src, const int* __restrict__ dst,
    int* __restrict__ bcur, int* __restrict__ packed, int E)
{
    __shared__ int hist[256];
    __shared__ int lstart[256];
    __shared__ int gbase[256];
    __shared__ int cur[256];
    __shared__ int sorted[PBLK];
    __shared__ unsigned char sbkt[PBLK];

    int tid = threadIdx.x;
    int lane = tid & 63;
    int e0 = blockIdx.x * PBLK;
    int cnt = min(PBLK, E - e0);

    hist[tid] = 0;
    __syncthreads();

    for (int i = tid; i < cnt; i += 256)
        atomicAdd(&hist[dst[e0 + i] >> 9], 1);
    __syncthreads();

    if (tid < 64) {
        int carry = 0;
        for (int c = 0; c < 4; ++c) {
            int v = hist[c * 64 + lane];
            int x = v;
            #pragma unroll
            for (int d = 1; d < 64; d <<= 1) { int t = __shfl_up(x, d); if (lane >= d) x += t; }
            lstart[c * 64 + lane] = x - v + carry;
            carry += __shfl(x, 63);
        }
    }
    __syncthreads();
    cur[tid] = lstart[tid];
    gbase[tid] = atomicAdd(&bcur[tid], hist[tid]);   // one reserve per bucket
    __syncthreads();

    // scatter into LDS, sorted by bucket (dst/src re-read: L2-hot, coalesced)
    for (int i = tid; i < cnt; i += 256) {
        int d = dst[e0 + i];
        int s = src[e0 + i];
        int b = d >> 9;
        int p = atomicAdd(&cur[b], 1);
        sorted[p] = ((d & 511) << 17) | s;
        sbkt[p] = (unsigned char)b;
    }
    __syncthreads();

    // write out: consecutive slots within a bucket -> consecutive global
    for (int i = tid; i < cnt; i += 256) {
        int b = sbkt[i];
        packed[gbase[b] + (i - lstart[b])] = sorted[i];
    }
}

// ---------------------------------------------------------------------------
// Kernel 4: per-bucket CSR: counting-sort ~8200 edges by 9 low dst bits in
// LDS, emit row_start + eord fully coalesced.
// ---------------------------------------------------------------------------
__global__ __launch_bounds__(256) void local_csr(
    const int* __restrict__ packed, const int* __restrict__ bbase,
    int* __restrict__ row_start, int* __restrict__ eord, int N)
{
    __shared__ int hist[512];
    __shared__ int excl[513];
    __shared__ int cur[512];
    __shared__ int stage[CSR_CAP];

    int b = blockIdx.x;
    int tid = threadIdx.x;
    int lane = tid & 63;
    int ebase = bbase[b];
    int ecnt  = bbase[b + 1] - ebase;

    hist[tid] = 0; hist[tid + 256] = 0;
    __syncthreads();

    for (int i = tid; i < ecnt; i += 256)
        atomicAdd(&hist[packed[ebase + i] >> 17], 1);
    __syncthreads();

    if (tid < 64) {
        int carry = 0;
        for (int c = 0; c < 8; ++c) {
            int v = hist[c * 64 + lane];
            int x = v;
            #pragma unroll
            for (int d = 1; d < 64; d <<= 1) { int t = __shfl_up(x, d); if (lane >= d) x += t; }
            excl[c * 64 + lane] = x - v + carry;
            carry += __shfl(x, 63);
        }
        if (lane == 0) excl[512] = carry;
    }
    __syncthreads();

    for (int j = tid; j <= 512; j += 256) {
        int node = b * 512 + j;
        if (node <= N) row_start[node] = ebase + excl[j];
    }
    cur[tid] = excl[tid]; cur[tid + 256] = excl[tid + 256];
    __syncthreads();

    for (int i = tid; i < ecnt; i += 256) {
        int v = packed[ebase + i];
        int lpos = atomicAdd(&cur[v >> 17], 1);
        int s = v & 0x1FFFF;
        if (lpos < CSR_CAP) stage[lpos] = s;          // LDS staging
        else eord[ebase + lpos] = s;                  // overflow (≈never)
    }
    __syncthreads();
    int m = min(ecnt, CSR_CAP);
    for (int i = tid; i < m; i += 256) eord[ebase + i] = stage[i];
}

// ---------------------------------------------------------------------------
// Kernel 5: gather.  v[i] = x[i] + sum_{j->i} xb[j] (bf16 neighbor reads,
// fp32 accumulate).  Wave per node, 8 independent accumulators.
// ---------------------------------------------------------------------------
__global__ __launch_bounds__(256) void gather_v(
    const float* __restrict__ x, const unsigned short* __restrict__ xb,
    const int* __restrict__ eord, const int* __restrict__ row_start,
    unsigned short* __restrict__ v_out, int N)
{
    int lane = threadIdx.x & 63;
    int wave = threadIdx.x >> 6;
    int stride = gridDim.x * 4;

    for (int node = blockIdx.x * 4 + wave; node < N; node += stride) {
        size_t row = (size_t)node * 64;
        int beg = row_start[node];
        int end = row_start[node + 1];

        float v0 = x[row + lane];
        float v1 = 0.f, v2 = 0.f, v3 = 0.f, v4 = 0.f, v5 = 0.f, v6 = 0.f, v7 = 0.f;

        for (int base = beg; base < end; base += 64) {
            int ei = (base + lane < end) ? eord[base + lane] : 0;
            int cnt = end - base; if (cnt > 64) cnt = 64;
            int j = 0;
            for (; j + 8 <= cnt; j += 8) {
                int s0 = __builtin_amdgcn_readlane(ei, j + 0);
                int s1 = __builtin_amdgcn_readlane(ei, j + 1);
                int s2 = __builtin_amdgcn_readlane(ei, j + 2);
                int s3 = __builtin_amdgcn_readlane(ei, j + 3);
                int s4 = __builtin_amdgcn_readlane(ei, j + 4);
                int s5 = __builtin_amdgcn_readlane(ei, j + 5);
                int s6 = __builtin_amdgcn_readlane(ei, j + 6);
                int s7 = __builtin_amdgcn_readlane(ei, j + 7);
                unsigned short t0 = xb[(size_t)s0 * 64 + lane];
                unsigned short t1 = xb[(size_t)s1 * 64 + lane];
                unsigned short t2 = xb[(size_t)s2 * 64 + lane];
                unsigned short t3 = xb[(size_t)s3 * 64 + lane];
                unsigned short t4 = xb[(size_t)s4 * 64 + lane];
                unsigned short t5 = xb[(size_t)s5 * 64 + lane];
                unsigned short t6 = xb[(size_t)s6 * 64 + lane];
                unsigned short t7 = xb[(size_t)s7 * 64 + lane];
                v0 += bf2f(t0); v1 += bf2f(t1); v2 += bf2f(t2); v3 += bf2f(t3);
                v4 += bf2f(t4); v5 += bf2f(t5); v6 += bf2f(t6); v7 += bf2f(t7);
            }
            for (; j < cnt; ++j) {
                int s = __builtin_amdgcn_readlane(ei, j);
                v1 += bf2f(xb[(size_t)s * 64 + lane]);
            }
        }
        float v = ((v0 + v1) + (v2 + v3)) + ((v4 + v5) + (v6 + v7));
        v_out[row + lane] = f2bf(v);
    }
}

// ---------------------------------------------------------------------------
// Kernel 6: MFMA MLP.  Each wave computes 16 nodes (see R5 notes).
// ---------------------------------------------------------------------------
__global__ __launch_bounds__(256) void mlp_mfma(
    const unsigned short* __restrict__ v,
    const float* __restrict__ W1, const float* __restrict__ b1,
    const float* __restrict__ W2, const float* __restrict__ b2,
    const float* __restrict__ Wg, const float* __restrict__ bg,
    unsigned short* __restrict__ h_out, float* __restrict__ gate_out, int N)
{
    int lane = threadIdx.x & 63;
    int wave = threadIdx.x >> 6;
    int quad = lane >> 4;
    int col  = lane & 15;

    s16x8 w1f[4][2], w2f[4][2];
    #pragma unroll
    for (int nt = 0; nt < 4; ++nt)
        #pragma unroll
        for (int kh = 0; kh < 2; ++kh) {
            s16x8 f1, f2;
            #pragma unroll
            for (int j = 0; j < 8; ++j) {
                int k = kh * 32 + quad * 8 + j;
                f1[j] = (short)f2bf(W1[k * 64 + nt * 16 + col]);
                f2[j] = (short)f2bf(W2[k * 64 + nt * 16 + col]);
            }
            w1f[nt][kh] = f1; w2f[nt][kh] = f2;
        }
    float b1v[4], b2v[4], wgv[4];
    #pragma unroll
    for (int nt = 0; nt < 4; ++nt) {
        b1v[nt] = b1[nt * 16 + col];
        b2v[nt] = b2[nt * 16 + col];
        wgv[nt] = Wg[nt * 16 + col];
    }
    float bgv = bg[0];

    __shared__ unsigned short h1s[4][16][72];
    unsigned short (*tile)[72] = h1s[wave];

    int base = blockIdx.x * 64 + wave * 16;

    const unsigned short* vrow = v + (size_t)(base + col) * 64;
    s16x8 a0 = *(const s16x8*)(vrow + quad * 8);
    s16x8 a1 = *(const s16x8*)(vrow + 32 + quad * 8);

    f32x4 acc[4];
    #pragma unroll
    for (int nt = 0; nt < 4; ++nt) {
        f32x4 c = {0.f, 0.f, 0.f, 0.f};
        c = __builtin_amdgcn_mfma_f32_16x16x32_bf16(a0, w1f[nt][0], c, 0, 0, 0);
        c = __builtin_amdgcn_mfma_f32_16x16x32_bf16(a1, w1f[nt][1], c, 0, 0, 0);
        acc[nt] = c;
    }

    #pragma unroll
    for (int nt = 0; nt < 4; ++nt)
        #pragma unroll
        for (int r = 0; r < 4; ++r) {
            float hv = fmaxf(acc[nt][r] + b1v[nt], 0.f);
            tile[quad * 4 + r][nt * 16 + col] = f2bf(hv);
        }

    s16x8 g0 = *(const s16x8*)&tile[col][quad * 8];
    s16x8 g1 = *(const s16x8*)&tile[col][32 + quad * 8];

    f32x4 acc2[4];
    #pragma unroll
    for (int nt = 0; nt < 4; ++nt) {
        f32x4 c = {0.f, 0.f, 0.f, 0.f};
        c = __builtin_amdgcn_mfma_f32_16x16x32_bf16(g0, w2f[nt][0], c, 0, 0, 0);
        c = __builtin_amdgcn_mfma_f32_16x16x32_bf16(g1, w2f[nt][1], c, 0, 0, 0);
        acc2[nt] = c;
    }

    float gp[4] = {0.f, 0.f, 0.f, 0.f};
    #pragma unroll
    for (int nt = 0; nt < 4; ++nt)
        #pragma unroll
        for (int r = 0; r < 4; ++r) {
            float hv = fmaxf(acc2[nt][r] + b2v[nt], 0.f);
            h_out[(size_t)(base + quad * 4 + r) * 64 + nt * 16 + col] = f2bf(hv);
            gp[r] = fmaf(hv, wgv[nt], gp[r]);
        }
    #pragma unroll
    for (int r = 0; r < 4; ++r) {
        float t = gp[r];
        t += __shfl_xor(t, 1);
        t += __shfl_xor(t, 2);
        t += __shfl_xor(t, 4);
        t += __shfl_xor(t, 8);
        int node = base + quad * 4 + r;
        if (col == 0 && node < N) gate_out[node] = t + bgv;
    }
}

// ---------------------------------------------------------------------------
// Kernel 7: per-graph softmax-attention pooling + BN(eval) + linear + lsm.
// ---------------------------------------------------------------------------
__global__ __launch_bounds__(256) void pool_final(
    const unsigned short* __restrict__ h, const float* __restrict__ gate,
    const int* __restrict__ batch,
    const float* __restrict__ gamma_, const float* __restrict__ beta_,
    const float* __restrict__ mean_, const float* __restrict__ var_,
    const float* __restrict__ Wl, const float* __restrict__ bl,
    float* __restrict__ out, int N)
{
    int g = blockIdx.x;
    int tid = threadIdx.x;

    int lo = 0, hi = N;
    while (lo < hi) { int mid = (lo + hi) >> 1; if (batch[mid] < g) lo = mid + 1; else hi = mid; }
    int start = lo;
    hi = N;
    while (lo < hi) { int mid = (lo + hi) >> 1; if (batch[mid] < g + 1) lo = mid + 1; else hi = mid; }
    int end = lo;

    __shared__ float red[4];
    __shared__ float pool_s[4 * 64];

    int lane = tid & 63;
    int wave = tid >> 6;

    float m = -FLT_MAX;
    for (int i = start + tid; i < end; i += 256) m = fmaxf(m, gate[i]);
    #pragma unroll
    for (int off = 32; off; off >>= 1) m = fmaxf(m, __shfl_xor(m, off));
    if (lane == 0) red[wave] = m;
    __syncthreads();
    m = fmaxf(fmaxf(red[0], red[1]), fmaxf(red[2], red[3]));
    __syncthreads();

    float s = 0.f;
    for (int i = start + tid; i < end; i += 256) s += expf(gate[i] - m);
    #pragma unroll
    for (int off = 32; off; off >>= 1) s += __shfl_xor(s, off);
    if (lane == 0) red[wave] = s;
    __syncthreads();
    s = red[0] + red[1] + red[2] + red[3];

    float a0 = 0.f, a1 = 0.f, a2 = 0.f, a3 = 0.f;
    int i = start + wave;
    for (; i + 12 < end; i += 16) {
        float e0 = expf(gate[i]      - m);
        float e1 = expf(gate[i + 4]  - m);
        float e2 = expf(gate[i + 8]  - m);
        float e3 = expf(gate[i + 12] - m);
        float t0 = bf2f(h[(size_t)(i)      * 64 + lane]);
        float t1 = bf2f(h[(size_t)(i + 4)  * 64 + lane]);
        float t2 = bf2f(h[(size_t)(i + 8)  * 64 + lane]);
        float t3 = bf2f(h[(size_t)(i + 12) * 64 + lane]);
        a0 = fmaf(e0, t0, a0);
        a1 = fmaf(e1, t1, a1);
        a2 = fmaf(e2, t2, a2);
        a3 = fmaf(e3, t3, a3);
    }
    for (; i < end; i += 4) {
        float e = expf(gate[i] - m);
        a0 = fmaf(e, bf2f(h[(size_t)i * 64 + lane]), a0);
    }
    pool_s[wave * 64 + lane] = (a0 + a1) + (a2 + a3);
    __syncthreads();

    if (wave == 0) {
        float p = pool_s[lane] + pool_s[64 + lane] + pool_s[128 + lane] + pool_s[192 + lane];
        p = (end > start) ? (p / s) : 0.f;
        float nrm = (p - mean_[lane]) / sqrtf(var_[lane] + BN_EPS) * gamma_[lane] + beta_[lane];
        float l0 = nrm * Wl[lane * 2 + 0];
        float l1 = nrm * Wl[lane * 2 + 1];
        #pragma unroll
        for (int off = 32; off; off >>= 1) {
            l0 += __shfl_xor(l0, off);
            l1 += __shfl_xor(l1, off);
        }
        if (lane == 0) {
            l0 += bl[0];
            l1 += bl[1];
            float mx = fmaxf(l0, l1);
            float lse = mx + logf(expf(l0 - mx) + expf(l1 - mx));
            out[g * 2 + 0] = l0 - lse;
            out[g * 2 + 1] = l1 - lse;
        }
    }
}

// ---------------------------------------------------------------------------
extern "C" void kernel_launch(void* const* d_in, const int* in_sizes, int n_in,
                              void* d_out, int out_size, void* d_ws, size_t ws_size,
                              hipStream_t stream)
{
    const float* x     = (const float*)d_in[0];
    const int*   eidx  = (const int*)d_in[1];   // [2, E]: row0=src, row1=dst
    const int*   batch = (const int*)d_in[2];
    const float* W1    = (const float*)d_in[3];
    const float* b1    = (const float*)d_in[4];
    const float* W2    = (const float*)d_in[5];
    const float* b2    = (const float*)d_in[6];
    const float* Wg    = (const float*)d_in[7];
    const float* bg    = (const float*)d_in[8];
    const float* bng   = (const float*)d_in[9];
    const float* bnb   = (const float*)d_in[10];
    const float* bnm   = (const float*)d_in[11];
    const float* bnv   = (const float*)d_in[12];
    const float* Wl    = (const float*)d_in[13];
    const float* bl    = (const float*)d_in[14];
    float* out = (float*)d_out;

    int N = in_sizes[0] / 64;        // requires N < 131072 for the 17-bit pack
    int E = in_sizes[1] / 2;
    int G = out_size / 2;
    int NP = ((N + 63) / 64) * 64;   // padded node count (64-node MLP tiles)
    int NBUCK = (N + 511) / 512;     // <= 256

    char* w = (char*)d_ws;
    unsigned short* v    = (unsigned short*)w;   w += (size_t)NP * 64 * sizeof(unsigned short);
    unsigned short* h    = (unsigned short*)w;   w += (size_t)NP * 64 * sizeof(unsigned short);
    float* gate     = (float*)w;                 w += (size_t)N * sizeof(float);
    int*   row_start= (int*)w;                   w += (size_t)(N + 2) * sizeof(int);
    int*   eord     = (int*)w;                   w += (size_t)E * sizeof(int);
    int*   bcount   = (int*)w;                   w += 256 * sizeof(int);
    int*   bbase    = (int*)w;                   w += 257 * sizeof(int);
    int*   bcur     = (int*)w;                   // 256 ints

    unsigned short* xb = h;          // alias: xb dead before mlp_mfma writes h
    int* packed = (int*)v;           // alias: packed dead before gather writes v

    const int* src = eidx;
    const int* dst = eidx + E;

    hipMemsetAsync(bcount, 0, 256 * sizeof(int), stream);

    cvt_bf16       <<<(N * 64 / 4 + 255) / 256, 256, 0, stream>>>(x, xb, N * 64 / 4);

    bucket_hist    <<<(E + 4095) / 4096, 256, 0, stream>>>(dst, bcount, E);
    bucket_scan    <<<1, 64, 0, stream>>>(bcount, bbase, bcur);
    partition_edges<<<(E + PBLK - 1) / PBLK, 256, 0, stream>>>(src, dst, bcur, packed, E);
    local_csr      <<<NBUCK, 256, 0, stream>>>(packed, bbase, row_start, eord, N);

    gather_v       <<<2048, 256, 0, stream>>>(x, xb, eord, row_start, v, N);

    mlp_mfma       <<<NP / 64, 256, 0, stream>>>(v, W1, b1, W2, b2, Wg, bg,
                                                 h, gate, N);

    pool_final     <<<G, 256, 0, stream>>>(h, gate, batch, bng, bnb, bnm, bnv,
                                           Wl, bl, out, N);
}

// Round 8
// 234.921 us; speedup vs baseline: 2.6021x; 1.0530x over previous
//
#include <hip/hip_runtime.h>
#include <math.h>
#include <float.h>

#define BN_EPS 1e-5f
#define PBLK 8192        // edges per partition block
#define BCAP 12288       // per-bucket arena capacity (expected max ~8600)
#define CSR_CAP 12288    // LDS staging capacity per bucket

typedef short s16x8 __attribute__((ext_vector_type(8)));
typedef float f32x4 __attribute__((ext_vector_type(4)));

__device__ __forceinline__ unsigned short f2bf(float f) {
    unsigned u = __float_as_uint(f);
    u += 0x7FFFu + ((u >> 16) & 1u);          // round-to-nearest-even
    return (unsigned short)(u >> 16);
}
__device__ __forceinline__ float bf2f(unsigned short b) {
    return __uint_as_float(((unsigned)b) << 16);
}
__device__ __forceinline__ float bflo(unsigned u) { return __uint_as_float(u << 16); }
__device__ __forceinline__ float bfhi(unsigned u) { return __uint_as_float(u & 0xFFFF0000u); }

// ---------------------------------------------------------------------------
// Kernel 1: fused prep.  Blocks [0,nx4): x fp32 -> xb bf16.  Block nx4:
// transpose W1 -> w1t bf16 (n-major).  Block nx4+1: W2 -> w2t + zero bcur0.
// ---------------------------------------------------------------------------
__global__ __launch_bounds__(256) void cvt_prep(
    const float* __restrict__ x, unsigned short* __restrict__ xb,
    const float* __restrict__ W1, const float* __restrict__ W2,
    unsigned short* __restrict__ w1t, unsigned short* __restrict__ w2t,
    int* __restrict__ bcur0, int nx4, int n4)
{
    int blk = blockIdx.x;
    int tid = threadIdx.x;
    if (blk < nx4) {
        int i = blk * 256 + tid;
        if (i < n4) {
            float4 f = *(const float4*)(x + (size_t)i * 4);
            ushort4 o;
            o.x = f2bf(f.x); o.y = f2bf(f.y); o.z = f2bf(f.z); o.w = f2bf(f.w);
            *(ushort4*)(xb + (size_t)i * 4) = o;
        }
    } else if (blk == nx4) {
        for (int idx = tid; idx < 4096; idx += 256) {
            int n = idx >> 6, k = idx & 63;
            w1t[idx] = f2bf(W1[k * 64 + n]);
        }
    } else {
        for (int idx = tid; idx < 4096; idx += 256) {
            int n = idx >> 6, k = idx & 63;
            w2t[idx] = f2bf(W2[k * 64 + n]);
        }
        bcur0[tid] = 0;
    }
}

// ---------------------------------------------------------------------------
// Kernel 2: partition edges into per-bucket arenas (bucket = dst>>9).
// Per block: LDS histogram + LDS counting-sort of PBLK edges, ONE global
// atomic per touched bucket to reserve an arena chunk, coalesced writeout.
// val = (dst&511)<<17 | src  (requires N < 131072).
// ---------------------------------------------------------------------------
__global__ __launch_bounds__(256) void partition_edges(
    const int* __restrict__ src, const int* __restrict__ dst,
    int* __restrict__ bcur0, int* __restrict__ packed2, int E)
{
    __shared__ int hist[256], lstart[256], goff[256], cur[256];
    __shared__ int sorted[PBLK];
    __shared__ unsigned char sbkt[PBLK];

    int tid = threadIdx.x;
    int lane = tid & 63;
    int e0 = blockIdx.x * PBLK;
    int cnt = min(PBLK, E - e0);

    hist[tid] = 0;
    __syncthreads();

    for (int i = tid; i < cnt; i += 256)
        atomicAdd(&hist[dst[e0 + i] >> 9], 1);
    __syncthreads();

    if (tid < 64) {
        int carry = 0;
        for (int c = 0; c < 4; ++c) {
            int v = hist[c * 64 + lane];
            int xv = v;
            #pragma unroll
            for (int d = 1; d < 64; d <<= 1) { int t = __shfl_up(xv, d); if (lane >= d) xv += t; }
            lstart[c * 64 + lane] = xv - v + carry;
            carry += __shfl(xv, 63);
        }
    }
    __syncthreads();
    cur[tid] = lstart[tid];
    if (hist[tid] > 0) goff[tid] = atomicAdd(&bcur0[tid], hist[tid]);
    __syncthreads();

    for (int i = tid; i < cnt; i += 256) {
        int d = dst[e0 + i];
        int s = src[e0 + i];
        int b = d >> 9;
        int p = atomicAdd(&cur[b], 1);
        sorted[p] = ((d & 511) << 17) | s;
        sbkt[p] = (unsigned char)b;
    }
    __syncthreads();

    for (int i = tid; i < cnt; i += 256) {
        int b = sbkt[i];
        packed2[(size_t)b * BCAP + goff[b] + (i - lstart[b])] = sorted[i];
    }
}

// ---------------------------------------------------------------------------
// Kernel 3: per-bucket CSR.  Re-derives bucket bases via in-block scan of
// the 196 counts (no separate scan kernel), LDS counting-sort by 9 low
// dst bits, coalesced row_start + eord emission.
// ---------------------------------------------------------------------------
__global__ __launch_bounds__(256) void local_csr(
    const int* __restrict__ packed2, const int* __restrict__ bcur0,
    int* __restrict__ row_start, int* __restrict__ eord, int N, int NBUCK)
{
    __shared__ int sbase[256];
    __shared__ int hist[512];
    __shared__ int excl[513];
    __shared__ int cur[512];
    __shared__ int stage[CSR_CAP];

    int b = blockIdx.x;
    int tid = threadIdx.x;
    int lane = tid & 63;

    if (tid < 64) {
        int carry = 0;
        for (int c = 0; c < 4; ++c) {
            int idx = c * 64 + lane;
            int v = (idx < NBUCK) ? bcur0[idx] : 0;
            int xv = v;
            #pragma unroll
            for (int d = 1; d < 64; d <<= 1) { int t = __shfl_up(xv, d); if (lane >= d) xv += t; }
            sbase[idx] = xv - v + carry;
            carry += __shfl(xv, 63);
        }
    }
    hist[tid] = 0; hist[tid + 256] = 0;
    __syncthreads();

    int ebase = sbase[b];
    int ecnt  = bcur0[b];
    const int* pk = packed2 + (size_t)b * BCAP;

    for (int i = tid; i < ecnt; i += 256)
        atomicAdd(&hist[pk[i] >> 17], 1);
    __syncthreads();

    if (tid < 64) {
        int carry = 0;
        for (int c = 0; c < 8; ++c) {
            int v = hist[c * 64 + lane];
            int xv = v;
            #pragma unroll
            for (int d = 1; d < 64; d <<= 1) { int t = __shfl_up(xv, d); if (lane >= d) xv += t; }
            excl[c * 64 + lane] = xv - v + carry;
            carry += __shfl(xv, 63);
        }
        if (lane == 0) excl[512] = carry;
    }
    __syncthreads();

    for (int j = tid; j <= 512; j += 256) {
        int node = b * 512 + j;
        if (node <= N) row_start[node] = ebase + excl[j];
    }
    cur[tid] = excl[tid]; cur[tid + 256] = excl[tid + 256];
    __syncthreads();

    for (int i = tid; i < ecnt; i += 256) {
        int v = pk[i];
        int lpos = atomicAdd(&cur[v >> 17], 1);
        int s = v & 0x1FFFF;
        if (lpos < CSR_CAP) stage[lpos] = s;
        else eord[ebase + lpos] = s;
    }
    __syncthreads();
    int m = min(ecnt, CSR_CAP);
    for (int i = tid; i < m; i += 256) eord[ebase + i] = stage[i];
}

// ---------------------------------------------------------------------------
// Kernel 4: gather.  Lane holds 4 features (uint2 = 4 bf16): 16 lanes per
// neighbor row, 4 neighbors per load round, 4 independent accumulator sets.
// Self term from xb (bf16).  Cross-group reduce via shfl_xor(16,32).
// ---------------------------------------------------------------------------
__global__ __launch_bounds__(256) void gather_v(
    const unsigned short* __restrict__ xb,
    const int* __restrict__ eord, const int* __restrict__ row_start,
    unsigned short* __restrict__ v_out, int N)
{
    int lane = threadIdx.x & 63;
    int wave = threadIdx.x >> 6;
    int li = lane & 15;
    int g  = lane >> 4;
    bool gb1 = (g & 1) != 0;
    bool gb2 = (g & 2) != 0;
    int stride = gridDim.x * 4;

    for (int node = blockIdx.x * 4 + wave; node < N; node += stride) {
        size_t row = (size_t)node * 64;
        int beg = row_start[node];
        int end = row_start[node + 1];

        float a0=0,a1=0,a2=0,a3=0;
        float b0=0,b1=0,b2=0,b3=0;
        float c0=0,c1=0,c2=0,c3=0;
        float d0=0,d1=0,d2=0,d3=0;

        {   // self term (counted once: g==0 only)
            uint2 u = *(const uint2*)(xb + row + 4 * li);
            if (g == 0) {
                a0 += bflo(u.x); a1 += bfhi(u.x);
                a2 += bflo(u.y); a3 += bfhi(u.y);
            }
        }

        for (int base = beg; base < end; base += 64) {
            int idx = base + lane;
            int ei = (idx < end) ? eord[idx] : 0;
            int cnt = end - base; if (cnt > 64) cnt = 64;
            int cnt4 = cnt & ~3;
            int j = 0;

#define RND(A0,A1,A2,A3,JJ)                                            \
            {   int e0_ = __builtin_amdgcn_readlane(ei, (JJ)+0);       \
                int e1_ = __builtin_amdgcn_readlane(ei, (JJ)+1);       \
                int e2_ = __builtin_amdgcn_readlane(ei, (JJ)+2);       \
                int e3_ = __builtin_amdgcn_readlane(ei, (JJ)+3);       \
                int lo_ = gb1 ? e1_ : e0_;                             \
                int hi_ = gb1 ? e3_ : e2_;                             \
                int s_  = gb2 ? hi_ : lo_;                             \
                uint2 u_ = *(const uint2*)(xb + (size_t)s_ * 64 + 4 * li); \
                A0 += bflo(u_.x); A1 += bfhi(u_.x);                    \
                A2 += bflo(u_.y); A3 += bfhi(u_.y); }

            for (; j + 16 <= cnt4; j += 16) {
                RND(a0,a1,a2,a3, j + 0)
                RND(b0,b1,b2,b3, j + 4)
                RND(c0,c1,c2,c3, j + 8)
                RND(d0,d1,d2,d3, j + 12)
            }
            for (; j < cnt4; j += 4) { RND(b0,b1,b2,b3, j) }
            for (; j < cnt; ++j) {
                int s_ = __builtin_amdgcn_readlane(ei, j);
                uint2 u_ = *(const uint2*)(xb + (size_t)s_ * 64 + 4 * li);
                if (g == 0) {
                    c0 += bflo(u_.x); c1 += bfhi(u_.x);
                    c2 += bflo(u_.y); c3 += bfhi(u_.y);
                }
            }
#undef RND
        }

        float f0 = (a0 + b0) + (c0 + d0);
        float f1 = (a1 + b1) + (c1 + d1);
        float f2 = (a2 + b2) + (c2 + d2);
        float f3 = (a3 + b3) + (c3 + d3);
        f0 += __shfl_xor(f0, 16); f0 += __shfl_xor(f0, 32);
        f1 += __shfl_xor(f1, 16); f1 += __shfl_xor(f1, 32);
        f2 += __shfl_xor(f2, 16); f2 += __shfl_xor(f2, 32);
        f3 += __shfl_xor(f3, 16); f3 += __shfl_xor(f3, 32);
        if (g == 0) {
            uint2 o;
            o.x = ((unsigned)f2bf(f1) << 16) | f2bf(f0);
            o.y = ((unsigned)f2bf(f3) << 16) | f2bf(f2);
            *(uint2*)(v_out + row + 4 * li) = o;
        }
    }
}

// ---------------------------------------------------------------------------
// Kernel 5: MFMA MLP, 16 nodes/wave.  Weight frags = vector b128 loads from
// pre-transposed bf16 w1t/w2t (n-major).
// ---------------------------------------------------------------------------
__global__ __launch_bounds__(256) void mlp_mfma(
    const unsigned short* __restrict__ v,
    const unsigned short* __restrict__ w1t, const unsigned short* __restrict__ w2t,
    const float* __restrict__ b1, const float* __restrict__ b2,
    const float* __restrict__ Wg, const float* __restrict__ bg,
    unsigned short* __restrict__ h_out, float* __restrict__ gate_out, int N)
{
    int lane = threadIdx.x & 63;
    int wave = threadIdx.x >> 6;
    int quad = lane >> 4;
    int col  = lane & 15;

    s16x8 w1f[4][2], w2f[4][2];
    #pragma unroll
    for (int nt = 0; nt < 4; ++nt)
        #pragma unroll
        for (int kh = 0; kh < 2; ++kh) {
            int off = (nt * 16 + col) * 64 + kh * 32 + quad * 8;
            w1f[nt][kh] = *(const s16x8*)(w1t + off);
            w2f[nt][kh] = *(const s16x8*)(w2t + off);
        }
    float b1v[4], b2v[4], wgv[4];
    #pragma unroll
    for (int nt = 0; nt < 4; ++nt) {
        b1v[nt] = b1[nt * 16 + col];
        b2v[nt] = b2[nt * 16 + col];
        wgv[nt] = Wg[nt * 16 + col];
    }
    float bgv = bg[0];

    __shared__ unsigned short h1s[4][16][72];   // row pad 64->72: no conflicts
    unsigned short (*tile)[72] = h1s[wave];

    int base = blockIdx.x * 64 + wave * 16;

    const unsigned short* vrow = v + (size_t)(base + col) * 64;
    s16x8 a0 = *(const s16x8*)(vrow + quad * 8);
    s16x8 a1 = *(const s16x8*)(vrow + 32 + quad * 8);

    f32x4 acc[4];
    #pragma unroll
    for (int nt = 0; nt < 4; ++nt) {
        f32x4 c = {0.f, 0.f, 0.f, 0.f};
        c = __builtin_amdgcn_mfma_f32_16x16x32_bf16(a0, w1f[nt][0], c, 0, 0, 0);
        c = __builtin_amdgcn_mfma_f32_16x16x32_bf16(a1, w1f[nt][1], c, 0, 0, 0);
        acc[nt] = c;
    }

    #pragma unroll
    for (int nt = 0; nt < 4; ++nt)
        #pragma unroll
        for (int r = 0; r < 4; ++r) {
            float hv = fmaxf(acc[nt][r] + b1v[nt], 0.f);
            tile[quad * 4 + r][nt * 16 + col] = f2bf(hv);
        }

    s16x8 g0 = *(const s16x8*)&tile[col][quad * 8];
    s16x8 g1 = *(const s16x8*)&tile[col][32 + quad * 8];

    f32x4 acc2[4];
    #pragma unroll
    for (int nt = 0; nt < 4; ++nt) {
        f32x4 c = {0.f, 0.f, 0.f, 0.f};
        c = __builtin_amdgcn_mfma_f32_16x16x32_bf16(g0, w2f[nt][0], c, 0, 0, 0);
        c = __builtin_amdgcn_mfma_f32_16x16x32_bf16(g1, w2f[nt][1], c, 0, 0, 0);
        acc2[nt] = c;
    }

    float gp[4] = {0.f, 0.f, 0.f, 0.f};
    #pragma unroll
    for (int nt = 0; nt < 4; ++nt)
        #pragma unroll
        for (int r = 0; r < 4; ++r) {
            float hv = fmaxf(acc2[nt][r] + b2v[nt], 0.f);
            h_out[(size_t)(base + quad * 4 + r) * 64 + nt * 16 + col] = f2bf(hv);
            gp[r] = fmaf(hv, wgv[nt], gp[r]);
        }
    #pragma unroll
    for (int r = 0; r < 4; ++r) {
        float t = gp[r];
        t += __shfl_xor(t, 1);
        t += __shfl_xor(t, 2);
        t += __shfl_xor(t, 4);
        t += __shfl_xor(t, 8);
        int node = base + quad * 4 + r;
        if (col == 0 && node < N) gate_out[node] = t + bgv;
    }
}

// ---------------------------------------------------------------------------
// Kernel 6: per-graph softmax-attention pooling + BN(eval) + linear + lsm.
// ---------------------------------------------------------------------------
__global__ __launch_bounds__(256) void pool_final(
    const unsigned short* __restrict__ h, const float* __restrict__ gate,
    const int* __restrict__ batch,
    const float* __restrict__ gamma_, const float* __restrict__ beta_,
    const float* __restrict__ mean_, const float* __restrict__ var_,
    const float* __restrict__ Wl, const float* __restrict__ bl,
    float* __restrict__ out, int N)
{
    int g = blockIdx.x;
    int tid = threadIdx.x;

    int lo = 0, hi = N;
    while (lo < hi) { int mid = (lo + hi) >> 1; if (batch[mid] < g) lo = mid + 1; else hi = mid; }
    int start = lo;
    hi = N;
    while (lo < hi) { int mid = (lo + hi) >> 1; if (batch[mid] < g + 1) lo = mid + 1; else hi = mid; }
    int end = lo;

    __shared__ float red[4];
    __shared__ float pool_s[4 * 64];

    int lane = tid & 63;
    int wave = tid >> 6;

    float m = -FLT_MAX;
    for (int i = start + tid; i < end; i += 256) m = fmaxf(m, gate[i]);
    #pragma unroll
    for (int off = 32; off; off >>= 1) m = fmaxf(m, __shfl_xor(m, off));
    if (lane == 0) red[wave] = m;
    __syncthreads();
    m = fmaxf(fmaxf(red[0], red[1]), fmaxf(red[2], red[3]));
    __syncthreads();

    float s = 0.f;
    for (int i = start + tid; i < end; i += 256) s += expf(gate[i] - m);
    #pragma unroll
    for (int off = 32; off; off >>= 1) s += __shfl_xor(s, off);
    if (lane == 0) red[wave] = s;
    __syncthreads();
    s = red[0] + red[1] + red[2] + red[3];

    float a0 = 0.f, a1 = 0.f, a2 = 0.f, a3 = 0.f;
    int i = start + wave;
    for (; i + 12 < end; i += 16) {
        float e0 = expf(gate[i]      - m);
        float e1 = expf(gate[i + 4]  - m);
        float e2 = expf(gate[i + 8]  - m);
        float e3 = expf(gate[i + 12] - m);
        float t0 = bf2f(h[(size_t)(i)      * 64 + lane]);
        float t1 = bf2f(h[(size_t)(i + 4)  * 64 + lane]);
        float t2 = bf2f(h[(size_t)(i + 8)  * 64 + lane]);
        float t3 = bf2f(h[(size_t)(i + 12) * 64 + lane]);
        a0 = fmaf(e0, t0, a0);
        a1 = fmaf(e1, t1, a1);
        a2 = fmaf(e2, t2, a2);
        a3 = fmaf(e3, t3, a3);
    }
    for (; i < end; i += 4) {
        float e = expf(gate[i] - m);
        a0 = fmaf(e, bf2f(h[(size_t)i * 64 + lane]), a0);
    }
    pool_s[wave * 64 + lane] = (a0 + a1) + (a2 + a3);
    __syncthreads();

    if (wave == 0) {
        float p = pool_s[lane] + pool_s[64 + lane] + pool_s[128 + lane] + pool_s[192 + lane];
        p = (end > start) ? (p / s) : 0.f;
        float nrm = (p - mean_[lane]) / sqrtf(var_[lane] + BN_EPS) * gamma_[lane] + beta_[lane];
        float l0 = nrm * Wl[lane * 2 + 0];
        float l1 = nrm * Wl[lane * 2 + 1];
        #pragma unroll
        for (int off = 32; off; off >>= 1) {
            l0 += __shfl_xor(l0, off);
            l1 += __shfl_xor(l1, off);
        }
        if (lane == 0) {
            l0 += bl[0];
            l1 += bl[1];
            float mx = fmaxf(l0, l1);
            float lse = mx + logf(expf(l0 - mx) + expf(l1 - mx));
            out[g * 2 + 0] = l0 - lse;
            out[g * 2 + 1] = l1 - lse;
        }
    }
}

// ---------------------------------------------------------------------------
extern "C" void kernel_launch(void* const* d_in, const int* in_sizes, int n_in,
                              void* d_out, int out_size, void* d_ws, size_t ws_size,
                              hipStream_t stream)
{
    const float* x     = (const float*)d_in[0];
    const int*   eidx  = (const int*)d_in[1];   // [2, E]: row0=src, row1=dst
    const int*   batch = (const int*)d_in[2];
    const float* W1    = (const float*)d_in[3];
    const float* b1    = (const float*)d_in[4];
    const float* W2    = (const float*)d_in[5];
    const float* b2    = (const float*)d_in[6];
    const float* Wg    = (const float*)d_in[7];
    const float* bg    = (const float*)d_in[8];
    const float* bng   = (const float*)d_in[9];
    const float* bnb   = (const float*)d_in[10];
    const float* bnm   = (const float*)d_in[11];
    const float* bnv   = (const float*)d_in[12];
    const float* Wl    = (const float*)d_in[13];
    const float* bl    = (const float*)d_in[14];
    float* out = (float*)d_out;

    int N = in_sizes[0] / 64;        // requires N < 131072 for the 17-bit pack
    int E = in_sizes[1] / 2;
    int G = out_size / 2;
    int NP = ((N + 63) / 64) * 64;   // padded node count (64-node MLP tiles)
    int NBUCK = (N + 511) / 512;     // <= 256

    char* w = (char*)d_ws;
    unsigned short* v    = (unsigned short*)w;   w += (size_t)NP * 64 * sizeof(unsigned short);
    unsigned short* h    = (unsigned short*)w;   w += (size_t)NP * 64 * sizeof(unsigned short);
    float* gate     = (float*)w;                 w += (size_t)N * sizeof(float);
    int*   row_start= (int*)w;                   w += (size_t)(N + 2) * sizeof(int);
    int*   eord     = (int*)w;                   w += (size_t)E * sizeof(int);
    int*   bcur0    = (int*)w;                   w += 256 * sizeof(int);
    unsigned short* w1t = (unsigned short*)w;    w += 4096 * sizeof(unsigned short);
    unsigned short* w2t = (unsigned short*)w;    // 4096 u16

    unsigned short* xb = h;          // alias: xb dead before mlp_mfma writes h
    int* packed2 = (int*)v;          // alias: NBUCK*BCAP*4 = 9.6 MB < v (12.8 MB)

    const int* src = eidx;
    const int* dst = eidx + E;

    int n4 = N * 16;                 // N*64/4 float4 groups
    int nx4 = (n4 + 255) / 256;

    cvt_prep       <<<nx4 + 2, 256, 0, stream>>>(x, xb, W1, W2, w1t, w2t,
                                                 bcur0, nx4, n4);

    partition_edges<<<(E + PBLK - 1) / PBLK, 256, 0, stream>>>(src, dst, bcur0,
                                                               packed2, E);

    local_csr      <<<NBUCK, 256, 0, stream>>>(packed2, bcur0, row_start,
                                               eord, N, NBUCK);

    gather_v       <<<2048, 256, 0, stream>>>(xb, eord, row_start, v, N);

    mlp_mfma       <<<NP / 64, 256, 0, stream>>>(v, w1t, w2t, b1, b2, Wg, bg,
                                                 h, gate, N);

    pool_final     <<<G, 256, 0, stream>>>(h, gate, batch, bng, bnb, bnm, bnv,
                                           Wl, bl, out, N);
}